// Round 10
// baseline (289.114 us; speedup 1.0000x reference)
//
#include <hip/hip_runtime.h>
#include <stdint.h>
#include <stddef.h>

// ---------------------------------------------------------------------------
// CausalSelfAttention forward, MI355X/gfx950.
// Pipeline: cvt3(fp32->bf16) -> GEMM1(qkv, 256x288 8-phase) ->
//           normrope_tv -> attn_fwd3(KVBLK=64, 512 blocks, 2/CU) ->
//           GEMM2(out proj, fp32, 128x192 8-phase)
// R14: attn TLP restructure. R13 showed launch overhead is small (~2.6us
//      for a launch removed) -> the ~80us gap is in-kernel, mostly attn
//      (~70us, just under the 75.5 cutoff, ~380 TF). Old attn: 256 blocks
//      = 1 block/CU, 8 barrier-locked waves -> serial chain exposed.
//      New: un-mirrored, 512 blocks (one qp-strip each) = 2 blocks/CU
//      (LDS 68.6KB: KV 48K + single-frag plds 20.5K; launch_bounds(512,4)
//      caps VGPR at 128 -- K frags read per-nt to shrink live set).
//      Dispatch remap: qp DESCENDING (LPT; ideal 34 units/CU >= max 32)
//      + same 4-bh-per-XCD K/V L2 grouping. Cost: 1.36x staged K/V (~+5us
//      at L2 BW), paid for by cross-block overlap of the serial chain.
//      gemm1/gemm2/cvt3/normrope_tv byte-identical to R13 (284.1us).
// ---------------------------------------------------------------------------

typedef __attribute__((ext_vector_type(8))) __bf16 bf16x8;
typedef __attribute__((ext_vector_type(4))) __bf16 bf16x4;
typedef __attribute__((ext_vector_type(4))) float  f32x4;

#define NB 2
#define NT 2048
#define NC 1536
#define NH 16
#define ND 96
#define NQKV 4608          // 3*NC
#define NM 4096            // NB*NT
#define NR_BLOCKS 16384    // (NB*NT*NH)/4 normrope-role blocks

static __device__ __forceinline__ float fexp2(float x) {
#if __has_builtin(__builtin_amdgcn_exp2f)
  return __builtin_amdgcn_exp2f(x);
#else
  return exp2f(x);
#endif
}

// async global->LDS, 16B per lane; LDS dest = wave-uniform base + lane*16
static __device__ __forceinline__ void g2lds16(const void* g, void* l) {
  __builtin_amdgcn_global_load_lds(
      (const __attribute__((address_space(1))) void*)g,
      (__attribute__((address_space(3))) void*)l, 16, 0, 0);
}

// ---------------------------------------------------------------------------
// fp32 -> bf16 conversion, all three tensors in one launch.
// ---------------------------------------------------------------------------
__global__ __launch_bounds__(256) void cvt3_f32_bf16(
    const float4* __restrict__ sx, bf16x4* __restrict__ dx, int n4x,
    const float4* __restrict__ sw, bf16x4* __restrict__ dw, int n4w,
    const float4* __restrict__ so, bf16x4* __restrict__ do_) {
  int i = blockIdx.x * 256 + threadIdx.x;
  const float4* s;
  bf16x4* d;
  if (i < n4x)            { s = sx + i;               d = dx + i; }
  else if (i < n4x + n4w) { s = sw + (i - n4x);       d = dw + (i - n4x); }
  else                    { s = so + (i - n4x - n4w); d = do_ + (i - n4x - n4w); }
  float4 v = *s;
  bf16x4 o;
  o[0] = (__bf16)v.x; o[1] = (__bf16)v.y;
  o[2] = (__bf16)v.z; o[3] = (__bf16)v.w;
  *d = o;
}

// ---------------------------------------------------------------------------
// shared 8-phase helpers
// ---------------------------------------------------------------------------
#define BAR1() do { __builtin_amdgcn_s_barrier(); \
                    asm volatile("" ::: "memory"); } while (0)
#define BAR2() do { asm volatile("" ::: "memory"); \
                    __builtin_amdgcn_s_barrier(); } while (0)
#define WAITLGKM() do { asm volatile("s_waitcnt lgkmcnt(0)" ::: "memory"); \
                        __builtin_amdgcn_sched_barrier(0); } while (0)
#define WAITVM6() asm volatile("s_waitcnt vmcnt(6)" ::: "memory")
#define WAITVM5() asm volatile("s_waitcnt vmcnt(5)" ::: "memory")

// ---------------------------------------------------------------------------
// GEMM1: 256x288 tile, BK=64, 8-phase schedule (R8 schedule, benched 75us).
// (byte-identical to R13)
// ---------------------------------------------------------------------------
template <int MH>
static __device__ __forceinline__ void readA2(
    bf16x8 (&aR)[2][2], const char* buf, int aro, int sk0, int sk1) {
#pragma unroll
  for (int i = 0; i < 2; ++i) {
    const char* p = buf + aro + (MH * 2 + i) * 2048;
    aR[i][0] = *(const bf16x8*)(p + sk0);
    aR[i][1] = *(const bf16x8*)(p + sk1);
  }
}
template <int NF0, int NN>
static __device__ __forceinline__ void readBN(
    bf16x8 (&bb)[NN][2], const char* buf, int bro, int sk0, int sk1) {
#pragma unroll
  for (int j = 0; j < NN; ++j) {
    const char* p = buf + bro + (NF0 + j) * 2048;
    bb[j][0] = *(const bf16x8*)(p + sk0);
    bb[j][1] = *(const bf16x8*)(p + sk1);
  }
}
template <int MH, int NF0, int NN>
static __device__ __forceinline__ void quadN(
    f32x4 (&acc)[4][9], const bf16x8 (&aR)[2][2], const bf16x8 (&bb)[NN][2]) {
  __builtin_amdgcn_s_setprio(1);
#pragma unroll
  for (int i = 0; i < 2; ++i)
#pragma unroll
    for (int j = 0; j < NN; ++j)
#pragma unroll
      for (int ks = 0; ks < 2; ++ks)
        acc[MH * 2 + i][NF0 + j] = __builtin_amdgcn_mfma_f32_16x16x32_bf16(
            aR[i][ks], bb[j][ks], acc[MH * 2 + i][NF0 + j], 0, 0, 0);
  __builtin_amdgcn_s_setprio(0);
}

__global__ __launch_bounds__(512, 2) void gemm1_8ph(
    const __bf16* __restrict__ A, const __bf16* __restrict__ Bw,
    __bf16* __restrict__ C, int M, int N, int K) {
  __shared__ __align__(16) char lds[139264];
  char* const A0 = lds;                 // 32KB
  char* const A1 = lds + 32768;         // 32KB
  char* const B0 = lds + 65536;         // 36KB
  char* const B1 = lds + 102400;        // 36KB

  const int tid = threadIdx.x;
  const int l   = tid & 63;
  const int w   = tid >> 6;        // 0..7
  const int wm  = w >> 1;          // 0..3 (M quarter, 64 rows)
  const int wn  = w & 1;           // 0..1 (N half, 144 cols)
  const int lm  = l & 15;
  const int lq  = l >> 4;

  // XCD-aware bijective tile swizzle (grid 16x16 = 256, %8==0)
  const int nnt = 16;
  const int nwg = gridDim.x * gridDim.y;        // 256
  const int lid = blockIdx.y * gridDim.x + blockIdx.x;
  const int swz = (lid & 7) * (nwg >> 3) + (lid >> 3);
  const int m0  = (swz / nnt) * 256;
  const int n0  = (swz % nnt) * 288;

  const int aro = (wm * 64 + lm) * 128;
  const int bro = (wn * 144 + lm) * 128;
  const int sk0 = ((lq) ^ (lm & 7)) * 16;
  const int sk1 = ((4 + lq) ^ (lm & 7)) * 16;

  const int ssl = ((l & 7) ^ ((l >> 3) & 7)) * 8;
  auto stageA = [&](int grow0, int k0, char* dst) {
#pragma unroll
    for (int q2 = 0; q2 < 2; ++q2) {
      const int c   = w * 2 + q2;
      const int row = c * 8 + (l >> 3);
      g2lds16(A + (size_t)(grow0 + row) * K + k0 + ssl, dst + c * 1024);
    }
  };
  auto stageB = [&](int grow0, int k0, char* dst) {
#pragma unroll
    for (int q2 = 0; q2 < 2; ++q2) {
      const int c   = w * 2 + q2;
      const int row = c * 8 + (l >> 3);
      g2lds16(Bw + (size_t)(grow0 + row) * K + k0 + ssl, dst + c * 1024);
    }
    if (w < 2) {
      const int c   = 16 + w;
      const int row = c * 8 + (l >> 3);
      g2lds16(Bw + (size_t)(grow0 + row) * K + k0 + ssl, dst + c * 1024);
    }
  };

  f32x4 acc[4][9] = {};
  bf16x8 aL[2][2], aH[2][2], b5[5][2], b4[4][2];

  // prologue: tile0 A0/B0 + hi-tile A1 (B1 staged in ph0-1 of iter 0)
  stageA(m0,       0,  A0);
  stageA(m0 + 128, 0,  A0 + 16384);
  stageB(n0,       0,  B0);
  stageB(n0 + 144, 0,  B0 + 18432);
  stageA(m0,       64, A1);
  stageA(m0 + 128, 64, A1 + 16384);

  const int NIT = K >> 7;   // 12 iterations x 2 K-tiles
  for (int it = 0; it < NIT; ++it) {
    const int kh  = it * 128 + 64;
    const int knl = it * 128 + 128;  // last iter: benign OOB-read into
    const int knh = it * 128 + 192;  //  adjacent workspace, never consumed
    // ph0: stage B1lo(kh); wait tile0 (A0+B0) landed; Q(Mlo,Nlo)
    stageB(n0, kh, B1);
    WAITVM6();
    BAR1();
    readA2<0>(aL, A0, aro, sk0, sk1);
    readBN<0, 5>(b5, B0, bro, sk0, sk1);
    WAITLGKM();
    quadN<0, 0, 5>(acc, aL, b5);
    BAR2();
    // ph1: Q(Mhi,Nlo)  (aL held for ph3)
    stageB(n0 + 144, kh, B1 + 18432);
    BAR1();
    readA2<1>(aH, A0, aro, sk0, sk1);
    WAITLGKM();
    quadN<1, 0, 5>(acc, aH, b5);
    BAR2();
    // ph2: stage A0'<-knl (A0 reads done ph1); Q(Mhi,Nhi)
    stageA(m0, knl, A0);
    BAR1();
    readBN<5, 4>(b4, B0, bro, sk0, sk1);
    WAITLGKM();
    quadN<1, 5, 4>(acc, aH, b4);
    BAR2();
    // ph3: Q(Mlo,Nhi)  (regs only)
    stageA(m0 + 128, knl, A0 + 16384);
    BAR1();
    quadN<0, 5, 4>(acc, aL, b4);
    BAR2();
    // ph4: hi K-tile (A1/B1); stage B0'<-knl (B0 reads done ph2)
    stageB(n0, knl, B0);
    WAITVM6();
    BAR1();
    readA2<0>(aL, A1, aro, sk0, sk1);
    readBN<0, 5>(b5, B1, bro, sk0, sk1);
    WAITLGKM();
    quadN<0, 0, 5>(acc, aL, b5);
    BAR2();
    // ph5
    stageB(n0 + 144, knl, B0 + 18432);
    BAR1();
    readA2<1>(aH, A1, aro, sk0, sk1);
    WAITLGKM();
    quadN<1, 0, 5>(acc, aH, b5);
    BAR2();
    // ph6: stage A1'<-knh (A1 reads done ph5)
    stageA(m0, knh, A1);
    BAR1();
    readBN<5, 4>(b4, B1, bro, sk0, sk1);
    WAITLGKM();
    quadN<1, 5, 4>(acc, aH, b4);
    BAR2();
    // ph7
    stageA(m0 + 128, knh, A1 + 16384);
    BAR1();
    quadN<0, 5, 4>(acc, aL, b4);
    BAR2();
  }

  // epilogue: C/D layout col=lane&15, row=(lane>>4)*4+r (m89/m91 verified)
  const int r0 = lq * 4;
#pragma unroll
  for (int mf = 0; mf < 4; ++mf)
#pragma unroll
    for (int nf = 0; nf < 9; ++nf)
#pragma unroll
      for (int r = 0; r < 4; ++r) {
        const size_t row = (size_t)(m0 + wm * 64 + mf * 16 + r0 + r);
        const size_t col = (size_t)(n0 + wn * 144 + nf * 16 + lm);
        C[row * N + col] = (__bf16)acc[mf][nf][r];
      }
}

// ---------------------------------------------------------------------------
// GEMM2: 128x192 tile, BK=64, 8-phase (R8 schedule), fp32 out.
// (byte-identical to R13)
// ---------------------------------------------------------------------------
template <int MH, int NF0, int NN>
static __device__ __forceinline__ void g2quad(
    f32x4 (&acc)[4][3], const bf16x8 (&aR)[2][2], const bf16x8 (&bb)[NN][2]) {
  __builtin_amdgcn_s_setprio(1);
#pragma unroll
  for (int i = 0; i < 2; ++i)
#pragma unroll
    for (int j = 0; j < NN; ++j)
#pragma unroll
      for (int ks = 0; ks < 2; ++ks)
        acc[MH * 2 + i][NF0 + j] = __builtin_amdgcn_mfma_f32_16x16x32_bf16(
            aR[i][ks], bb[j][ks], acc[MH * 2 + i][NF0 + j], 0, 0, 0);
  __builtin_amdgcn_s_setprio(0);
}

__global__ __launch_bounds__(512, 2) void gemm2_8ph(
    const __bf16* __restrict__ A, const __bf16* __restrict__ Bw,
    float* __restrict__ C, int M, int N, int K) {
  __shared__ __align__(16) char lds[81920];
  char* const A0 = lds;                 // 16KB
  char* const A1 = lds + 16384;         // 16KB
  char* const B0 = lds + 32768;         // 24KB
  char* const B1 = lds + 57344;         // 24KB

  const int tid = threadIdx.x;
  const int l   = tid & 63;
  const int w   = tid >> 6;        // 0..7
  const int wm  = w >> 2;          // 0..1 (M half)
  const int wn  = w & 3;           // 0..3 (N quarter)
  const int lm  = l & 15;
  const int lq  = l >> 4;

  const int nwg = gridDim.x * gridDim.y;        // 256
  const int lid = blockIdx.y * gridDim.x + blockIdx.x;
  const int swz = (lid & 7) * (nwg >> 3) + (lid >> 3);
  const int m0  = (swz / 8) * 128;
  const int n0  = (swz % 8) * 192;

  const int aro = (wm * 64 + lm) * 128;
  const int bro = (wn * 48 + lm) * 128;
  const int sk0 = ((lq) ^ (lm & 7)) * 16;
  const int sk1 = ((4 + lq) ^ (lm & 7)) * 16;

  const int ssl = ((l & 7) ^ ((l >> 3) & 7)) * 8;
  auto stageA = [&](int k0, char* dst) {          // 16 granules, 2/wave
#pragma unroll
    for (int q2 = 0; q2 < 2; ++q2) {
      const int c   = w * 2 + q2;
      const int row = c * 8 + (l >> 3);
      g2lds16(A + (size_t)(m0 + row) * K + k0 + ssl, dst + c * 1024);
    }
  };
  auto stageB = [&](int k0, char* dst) {          // 24 granules, 3/wave
#pragma unroll
    for (int q2 = 0; q2 < 3; ++q2) {
      const int c   = w * 3 + q2;
      const int row = c * 8 + (l >> 3);
      g2lds16(Bw + (size_t)(n0 + row) * K + k0 + ssl, dst + c * 1024);
    }
  };

  f32x4 acc[4][3] = {};
  bf16x8 aL[2][2], aH[2][2], bL[2][2], bH[1][2];

  // prologue: A0/B0 (tile lo) + A1 (tile hi); B1 staged in ph0 of iter 0.
  stageA(0,  A0);
  stageB(0,  B0);
  stageA(64, A1);                       // 7 outstanding/wave

  const int NIT = K >> 7;   // 12 iterations x 2 K-tiles
  for (int it = 0; it < NIT; ++it) {
    const int kh  = it * 128 + 64;
    const int knl = it * 128 + 128;  // last iter: benign OOB-read
    const int knh = it * 128 + 192;
    // ph0: stage B1<-kh; wait lo tile (A0+B0); Q(Mlo,Nlo01)
    stageB(kh, B1);
    WAITVM5();
    BAR1();
    readA2<0>(aL, A0, aro, sk0, sk1);
    readBN<0, 2>(bL, B0, bro, sk0, sk1);
    WAITLGKM();
    g2quad<0, 0, 2>(acc, aL, bL);
    BAR2();
    // ph1: Q(Mhi,Nlo01)
    BAR1();
    readA2<1>(aH, A0, aro, sk0, sk1);
    WAITLGKM();
    g2quad<1, 0, 2>(acc, aH, bL);
    BAR2();
    // ph2: stage A0<-knl (A0 reads done ph1); Q(Mhi,Nhi2)
    stageA(knl, A0);
    BAR1();
    readBN<2, 1>(bH, B0, bro, sk0, sk1);
    WAITLGKM();
    g2quad<1, 2, 1>(acc, aH, bH);
    BAR2();
    // ph3: Q(Mlo,Nhi2) (regs only)
    BAR1();
    g2quad<0, 2, 1>(acc, aL, bH);
    BAR2();
    // ph4: hi K-tile; stage B0<-knl (B0 reads done ph2); wait A1+B1
    stageB(knl, B0);
    WAITVM5();
    BAR1();
    readA2<0>(aL, A1, aro, sk0, sk1);
    readBN<0, 2>(bL, B1, bro, sk0, sk1);
    WAITLGKM();
    g2quad<0, 0, 2>(acc, aL, bL);
    BAR2();
    // ph5
    BAR1();
    readA2<1>(aH, A1, aro, sk0, sk1);
    WAITLGKM();
    g2quad<1, 0, 2>(acc, aH, bL);
    BAR2();
    // ph6: stage A1<-knh (A1 reads done ph5)
    stageA(knh, A1);
    BAR1();
    readBN<2, 1>(bH, B1, bro, sk0, sk1);
    WAITLGKM();
    g2quad<1, 2, 1>(acc, aH, bH);
    BAR2();
    // ph7
    BAR1();
    g2quad<0, 2, 1>(acc, aL, bH);
    BAR2();
  }

  // epilogue: fp32 stores; 192*4B tile pitch = whole 128B lines.
  const int r0 = lq * 4;
#pragma unroll
  for (int mf = 0; mf < 4; ++mf)
#pragma unroll
    for (int nf = 0; nf < 3; ++nf)
#pragma unroll
      for (int r = 0; r < 4; ++r) {
        const size_t row = (size_t)(m0 + wm * 64 + mf * 16 + r0 + r);
        const size_t col = (size_t)(n0 + wn * 48 + nf * 16 + lm);
        C[row * N + col] = acc[mf][nf][r];
      }
}

// ---------------------------------------------------------------------------
// Fused: qk RMS-norm + 3D RoPE (blocks 0..NR_BLOCKS-1) AND V transpose
// (blocks NR_BLOCKS..NR_BLOCKS+1023). (byte-identical to R13)
// ---------------------------------------------------------------------------
static __device__ __forceinline__ float rope_one(float v, float p, int d,
                                                 const float* c3) {
  const int a  = d >> 5;        // which of 3 coord axes (d3=32)
  const int j  = d & 31;
  const int jj = j & 15;        // half=16
  const float invf = fexp2((float)jj * -0.8304820237218406f);
  const float ang  = c3[a] * invf;
  float sn, cs;
  __sincosf(ang, &sn, &cs);
  return (j < 16) ? (v * cs - p * sn) : (v * cs + p * sn);
}

__global__ __launch_bounds__(256) void normrope_tv(
    const __bf16* __restrict__ qkv, const float* __restrict__ coords,
    const int* __restrict__ ttype, const float* __restrict__ qsc,
    const float* __restrict__ ksc, __bf16* __restrict__ qo,
    __bf16* __restrict__ ko, __bf16* __restrict__ vo) {
  __shared__ __align__(16) __bf16 tile[96][72];   // tv role only (13.8KB)
  if ((int)blockIdx.x < NR_BLOCKS) {
    // ---- normrope role ----
    const int l   = threadIdx.x & 63;
    const int w   = threadIdx.x >> 6;
    const int rid = blockIdx.x * 4 + w;       // (b*T+t)*H + h
    const int h   = rid & (NH - 1);
    const int bt  = rid >> 4;
    const int t   = bt & (NT - 1);
    const int b   = bt >> 11;                 // T = 2048
    const __bf16* base = qkv + (size_t)bt * NQKV + h * ND;
    const float*  c3   = coords + (size_t)bt * 3;
    const bool rope    = ttype[bt] > 0;
    const size_t bh    = (size_t)(b * NH + h);

    // ---- q ----
    {
      float x0 = (float)base[l];
      float x1 = (l < 32) ? (float)base[64 + l] : 0.f;
      float ss = x0 * x0 + x1 * x1;
#pragma unroll
      for (int off = 1; off < 64; off <<= 1) ss += __shfl_xor(ss, off, 64);
      const float rn = rsqrtf(ss * (1.f / 96.f) + 1e-6f);
      x0 *= rn * qsc[l];
      if (l < 32) x1 *= rn * qsc[64 + l];
      const float p0 = __shfl_xor(x0, 16, 64);
      const float p1 = __shfl_xor(x1, 16, 64);
      if (rope) {
        x0 = rope_one(x0, p0, l, c3);
        if (l < 32) x1 = rope_one(x1, p1, 64 + l, c3);
      }
      __bf16* dst = qo + (bh * NT + t) * ND;
      dst[l] = (__bf16)x0;
      if (l < 32) dst[64 + l] = (__bf16)x1;
    }
    // ---- k ----
    {
      float x0 = (float)base[NC + l];
      float x1 = (l < 32) ? (float)base[NC + 64 + l] : 0.f;
      float ss = x0 * x0 + x1 * x1;
#pragma unroll
      for (int off = 1; off < 64; off <<= 1) ss += __shfl_xor(ss, off, 64);
      const float rn = rsqrtf(ss * (1.f / 96.f) + 1e-6f);
      x0 *= rn * ksc[l];
      if (l < 32) x1 *= rn * ksc[64 + l];
      const float p0 = __shfl_xor(x0, 16, 64);
      const float p1 = __shfl_xor(x1, 16, 64);
      if (rope) {
        x0 = rope_one(x0, p0, l, c3);
        if (l < 32) x1 = rope_one(x1, p1, 64 + l, c3);
      }
      __bf16* dst = ko + (bh * NT + t) * ND;
      dst[l] = (__bf16)x0;
      if (l < 32) dst[64 + l] = (__bf16)x1;
    }
    return;
  }
  // ---- tv role: 64-token transpose tile ----
  const int bx2 = blockIdx.x - NR_BLOCKS;   // 0..1023
  const int bh  = bx2 >> 5;                 // 0..31
  const int t0  = (bx2 & 31) * 64;
  const int tid = threadIdx.x;
  const int tok = tid & 63;
  const int grp = tid >> 6;                 // 0..3
  const int b   = bh >> 4, h = bh & 15;
  const __bf16* src =
      qkv + ((size_t)(b * NT + t0 + tok)) * NQKV + 2 * NC + h * ND;
#pragma unroll
  for (int q2 = 0; q2 < 3; ++q2) {
    const int ch = grp * 3 + q2;            // 12 chunks of 8 d
    bf16x8 v = *(const bf16x8*)(src + ch * 8);
#pragma unroll
    for (int j = 0; j < 8; ++j) tile[ch * 8 + j][tok] = v[j];
  }
  __syncthreads();
#pragma unroll
  for (int k2 = 0; k2 < 3; ++k2) {
    const int c  = tid + k2 * 256;          // 0..767
    const int d  = c >> 3;                  // 0..95
    const int tc = c & 7;                   // 0..7
    bf16x8 v = *(const bf16x8*)(&tile[d][tc * 8]);
    *(bf16x8*)(vo + ((size_t)bh * ND + d) * NT + t0 + tc * 8) = v;
  }
}

// ---------------------------------------------------------------------------
// Flash attention, KVBLK=64, fixed-max softmax, LDS-staged K/V (dbuf).
// R14: un-mirrored, 512 blocks (one qp-strip each), 2 blocks/CU.
// LDS 68.6KB = KV 48K + plds[8][2][16][40] 20.5K. K frags read per-nt
// (12 live VGPR instead of 48) to fit launch_bounds(512,4) (<=128 VGPR).
// Block remap: grid (8,64); xcd = bx; bh = bx + 8*(by&3) (4 bh/XCD, K/V
// L2-shared); qp = 15 - (by>>2) -> longest blocks dispatch FIRST (LPT).
// ---------------------------------------------------------------------------
__global__ __launch_bounds__(512, 4) void attn_fwd3(
    const __bf16* __restrict__ q, const __bf16* __restrict__ k,
    const __bf16* __restrict__ vt, __bf16* __restrict__ out) {
  __shared__ __align__(16) char KV[2][24576];        // [buf][K 12KB | V 12KB]
  __shared__ __align__(16) __bf16 plds[8][2][16][40];
  const int tid = threadIdx.x;
  const int l   = tid & 63;
  const int w   = tid >> 6;          // 0..7
  const int bx  = blockIdx.x;        // 0..7  (= XCD)
  const int by  = blockIdx.y;        // 0..63
  const int bh  = bx + 8 * (by & 3);
  const int qp  = 15 - (by >> 2);    // descending with dispatch order

  const int lm  = l & 15;
  const int lq  = l >> 4;
  const int q0  = qp * 128 + w * 16;
  const int nktw = qp * 2 + (w >> 2) + 1;   // causal 64-tiles for this wave
  const int nkt  = qp * 2 + 2;              // block loop bound
  const __bf16* qh = q  + (size_t)bh * NT * ND;
  const __bf16* kh = k  + (size_t)bh * NT * ND;
  const __bf16* vh = vt + (size_t)bh * ND * NT;
  __bf16* pb = &plds[w][0][0][0];

  // stage one 64-key tile: 24 granules of 1KB, 3 per wave (wave-uniform).
  auto stage = [&](int n0, char* buf) {
#pragma unroll
    for (int q2 = 0; q2 < 3; ++q2) {
      const int g = w * 3 + q2;
      if (g < 12) {                  // K granules (wave-uniform branch)
        const int nt = g / 3, c = g - nt * 3;
        g2lds16(kh + (size_t)(n0 + nt * 16 + (l >> 2)) * ND + c * 32 + (l & 3) * 8,
                buf + g * 1024);
      } else {                       // V granules
        const int gv = g - 12;
        const int dt = gv >> 1, hf = gv & 1;
        g2lds16(vh + (size_t)(dt * 16 + (l >> 2)) * NT + n0 + hf * 32 + (l & 3) * 8,
                buf + 12288 + gv * 1024);
      }
    }
  };

  bf16x8 aq[3];
#pragma unroll
  for (int c = 0; c < 3; ++c)
    aq[c] = *(const bf16x8*)(qh + (size_t)(q0 + lm) * ND + c * 32 + lq * 8);

  f32x4 o[6] = {};
  f32x4 ls = {};
  const int ji = (lm * 4 + lq) * 16;   // this lane's granule byte offset
  const float cl = 0.10206207261596575f * 1.4426950408889634f;

  stage(0, KV[0]);
  for (int kt = 0; kt < nkt; ++kt) {
    __syncthreads();                   // drains stage(kt); all waves done kt-1
    if (kt + 1 < nkt) stage((kt + 1) * 64, KV[(kt + 1) & 1]);
    const char* Kc = KV[kt & 1];
    const char* Vc = KV[kt & 1] + 12288;
    const int n0 = kt * 64;
    const bool doW = kt < nktw;        // wave-uniform
    if (doW) {
      f32x4 s[4];
#pragma unroll
      for (int nt = 0; nt < 4; ++nt) {
        f32x4 a = {};
#pragma unroll
        for (int c = 0; c < 3; ++c) {
          bf16x8 bk = *(const bf16x8*)(Kc + (nt * 3 + c) * 1024 + ji);
          a = __builtin_amdgcn_mfma_f32_16x16x32_bf16(aq[c], bk, a, 0, 0, 0);
        }
        s[nt] = a;
      }
      if (n0 + 63 > q0) {   // diagonal-straddling tile(s): causal mask
#pragma unroll
        for (int nt = 0; nt < 4; ++nt)
#pragma unroll
          for (int r = 0; r < 4; ++r)
            if (n0 + nt * 16 + lm > q0 + lq * 4 + r) s[nt][r] = -1e30f;
      }
#pragma unroll
      for (int nt = 0; nt < 4; ++nt)
#pragma unroll
        for (int r = 0; r < 4; ++r)
          s[nt][r] = fexp2((s[nt][r] - 96.0f) * cl);
#pragma unroll
      for (int r = 0; r < 4; ++r)
        ls[r] += (s[0][r] + s[1][r]) + (s[2][r] + s[3][r]);
#pragma unroll
      for (int nt = 0; nt < 4; ++nt)
#pragma unroll
        for (int r = 0; r < 4; ++r)
          pb[(nt >> 1) * 640 + (lq * 4 + r) * 40 + (nt & 1) * 16 + lm] =
              (__bf16)s[nt][r];
      bf16x8 ap0 = *(const bf16x8*)(pb + lm * 40 + lq * 8);
      bf16x8 ap1 = *(const bf16x8*)(pb + 640 + lm * 40 + lq * 8);
#pragma unroll
      for (int dt = 0; dt < 6; ++dt) {
        bf16x8 bv0 = *(const bf16x8*)(Vc + (dt * 2 + 0) * 1024 + ji);
        bf16x8 bv1 = *(const bf16x8*)(Vc + (dt * 2 + 1) * 1024 + ji);
        o[dt] = __builtin_amdgcn_mfma_f32_16x16x32_bf16(ap0, bv0, o[dt], 0, 0, 0);
        o[dt] = __builtin_amdgcn_mfma_f32_16x16x32_bf16(ap1, bv1, o[dt], 0, 0, 0);
      }
    }
  }

  // epilogue: out[(b*T+t), h*96+d]
  const int b = bh >> 4, h = bh & 15;
  float rl[4];
#pragma unroll
  for (int r = 0; r < 4; ++r) {
    float v = ls[r];
#pragma unroll
    for (int off = 1; off < 16; off <<= 1) v += __shfl_xor(v, off, 64);
    rl[r] = 1.f / v;
  }
#pragma unroll
  for (int dt = 0; dt < 6; ++dt)
#pragma unroll
    for (int r = 0; r < 4; ++r) {
      const int t = q0 + lq * 4 + r;
      out[((size_t)(b * NT + t)) * NC + h * ND + dt * 16 + lm] =
          (__bf16)(o[dt][r] * rl[r]);
    }
}

// ---------------------------------------------------------------------------
// workspace layout (bytes); attn-out aliases xb (dead after GEMM1)
// ---------------------------------------------------------------------------
static constexpr size_t OFF_XB   = 0;          // 12,582,912  (also attn out)
static constexpr size_t OFF_WQKV = 12582912;   // 14,155,776
static constexpr size_t OFF_WOUT = 26738688;   //  4,718,592
static constexpr size_t OFF_QKV  = 31457280;   // 37,748,736
static constexpr size_t OFF_Q    = 69206016;   // 12,582,912
static constexpr size_t OFF_K    = 81788928;   // 12,582,912
static constexpr size_t OFF_VT   = 94371840;   // 12,582,912  -> end 106,954,752

extern "C" void kernel_launch(void* const* d_in, const int* in_sizes, int n_in,
                              void* d_out, int out_size, void* d_ws,
                              size_t ws_size, hipStream_t stream) {
  const float* x      = (const float*)d_in[0];
  const float* coords = (const float*)d_in[1];
  const int*   ttype  = (const int*)d_in[2];
  const float* wqkv   = (const float*)d_in[3];
  const float* wout   = (const float*)d_in[4];
  const float* qs     = (const float*)d_in[5];
  const float* ks     = (const float*)d_in[6];

  char* ws = (char*)d_ws;
  __bf16* xb    = (__bf16*)(ws + OFF_XB);
  __bf16* wqkvb = (__bf16*)(ws + OFF_WQKV);
  __bf16* woutb = (__bf16*)(ws + OFF_WOUT);
  __bf16* qkvb  = (__bf16*)(ws + OFF_QKV);
  __bf16* qb    = (__bf16*)(ws + OFF_Q);
  __bf16* kb    = (__bf16*)(ws + OFF_K);
  __bf16* vtb   = (__bf16*)(ws + OFF_VT);
  __bf16* attnb = (__bf16*)(ws + OFF_XB);   // alias

  // 1. fp32 -> bf16 conversions (single launch)
  {
    const int n4x = NM * NC / 4;            // 1,572,864
    const int n4w = NQKV * NC / 4;          // 1,769,472
    const int n4o = NC * NC / 4;            //   589,824
    const int nblk = (n4x + n4w + n4o) / 256;
    cvt3_f32_bf16<<<nblk, 256, 0, stream>>>(
        (const float4*)x, (bf16x4*)xb, n4x,
        (const float4*)wqkv, (bf16x4*)wqkvb, n4w,
        (const float4*)wout, (bf16x4*)woutb);
  }
  // 2. qkv = x @ W_qkv^T  (bf16 out, 256x288 8-phase, grid 16x16=256)
  gemm1_8ph<<<dim3(NQKV / 288, NM / 256), 512, 0, stream>>>(
      xb, wqkvb, qkvb, NM, NQKV, NC);
  // 3. fused qk-norm+rope AND v-transpose (one launch)
  normrope_tv<<<NR_BLOCKS + 1024, 256, 0, stream>>>(
      qkvb, coords, ttype, qs, ks, qb, kb, vtb);
  // 4. causal attention (KVBLK=64, 512 blocks @ 2/CU, LPT dispatch)
  attn_fwd3<<<dim3(8, 64), 512, 0, stream>>>(qb, kb, vtb, attnb);
  // 5. out = attn @ W_out^T (fp32 out, 128x192 8-phase, grid 8x32=256)
  gemm2_8ph<<<dim3(NC / 192, NM / 128), 512, 0, stream>>>(
      attnb, woutb, (float*)d_out, NM, NC, NC);
}

// Round 11
// 285.345 us; speedup vs baseline: 1.0132x; 1.0132x over previous
//
#include <hip/hip_runtime.h>
#include <stdint.h>
#include <stddef.h>

// ---------------------------------------------------------------------------
// CausalSelfAttention forward, MI355X/gfx950.
// Pipeline: cvt3(fp32->bf16) -> GEMM1(qkv, 256x288 8-phase) ->
//           normrope_tv -> attn_fwd2(KVBLK=64, mirrored, XCD-remap) ->
//           GEMM2(out proj, fp32, 128x96 8-phase, 2 blocks/CU)
// R15: (1) attn reverted to R13's mirrored attn_fwd2 (R14's 2/CU variant
//      regressed +5us: 1.36x staged K/V + lost mirror-sharing > overlap).
//      (2) Budget analysis: components sum ~183 + gemm2 => gemm2 ~45-60us
//      (only 6 MFMA/wave/phase vs gemm1's 18 -> phase-overhead-dominated),
//      AND gemm2 runs 1 block/CU (no co-resident block to hide stalls;
//      m97's 874 TF came from ~3 blocks/CU co-residency, m114 overlap).
//      New gemm2: 128x96 tile, 4 waves (256 thr), grid 16x32=512 blocks
//      = exactly 2/CU (LDS 56KB). Same R8 schedule; staging A=4,B=3
//      granules/wave (uniform); FIFO re-derived: vmcnt(7) at ph0/ph4
//      (14 outstanding -> keep exactly next tile's 7). Unlike R14-attn,
//      duplication is only L2-resident B-panel reads (cheap).
// ---------------------------------------------------------------------------

typedef __attribute__((ext_vector_type(8))) __bf16 bf16x8;
typedef __attribute__((ext_vector_type(4))) __bf16 bf16x4;
typedef __attribute__((ext_vector_type(4))) float  f32x4;

#define NB 2
#define NT 2048
#define NC 1536
#define NH 16
#define ND 96
#define NQKV 4608          // 3*NC
#define NM 4096            // NB*NT
#define NR_BLOCKS 16384    // (NB*NT*NH)/4 normrope-role blocks

static __device__ __forceinline__ float fexp2(float x) {
#if __has_builtin(__builtin_amdgcn_exp2f)
  return __builtin_amdgcn_exp2f(x);
#else
  return exp2f(x);
#endif
}

// async global->LDS, 16B per lane; LDS dest = wave-uniform base + lane*16
static __device__ __forceinline__ void g2lds16(const void* g, void* l) {
  __builtin_amdgcn_global_load_lds(
      (const __attribute__((address_space(1))) void*)g,
      (__attribute__((address_space(3))) void*)l, 16, 0, 0);
}

// ---------------------------------------------------------------------------
// fp32 -> bf16 conversion, all three tensors in one launch.
// ---------------------------------------------------------------------------
__global__ __launch_bounds__(256) void cvt3_f32_bf16(
    const float4* __restrict__ sx, bf16x4* __restrict__ dx, int n4x,
    const float4* __restrict__ sw, bf16x4* __restrict__ dw, int n4w,
    const float4* __restrict__ so, bf16x4* __restrict__ do_) {
  int i = blockIdx.x * 256 + threadIdx.x;
  const float4* s;
  bf16x4* d;
  if (i < n4x)            { s = sx + i;               d = dx + i; }
  else if (i < n4x + n4w) { s = sw + (i - n4x);       d = dw + (i - n4x); }
  else                    { s = so + (i - n4x - n4w); d = do_ + (i - n4x - n4w); }
  float4 v = *s;
  bf16x4 o;
  o[0] = (__bf16)v.x; o[1] = (__bf16)v.y;
  o[2] = (__bf16)v.z; o[3] = (__bf16)v.w;
  *d = o;
}

// ---------------------------------------------------------------------------
// shared 8-phase helpers
// ---------------------------------------------------------------------------
#define BAR1() do { __builtin_amdgcn_s_barrier(); \
                    asm volatile("" ::: "memory"); } while (0)
#define BAR2() do { asm volatile("" ::: "memory"); \
                    __builtin_amdgcn_s_barrier(); } while (0)
#define WAITLGKM() do { asm volatile("s_waitcnt lgkmcnt(0)" ::: "memory"); \
                        __builtin_amdgcn_sched_barrier(0); } while (0)
#define WAITVM6() asm volatile("s_waitcnt vmcnt(6)" ::: "memory")
#define WAITVM7() asm volatile("s_waitcnt vmcnt(7)" ::: "memory")

// ---------------------------------------------------------------------------
// GEMM1: 256x288 tile, BK=64, 8-phase schedule (R8 schedule, benched 75us).
// (byte-identical to R13)
// ---------------------------------------------------------------------------
template <int MH>
static __device__ __forceinline__ void readA2(
    bf16x8 (&aR)[2][2], const char* buf, int aro, int sk0, int sk1) {
#pragma unroll
  for (int i = 0; i < 2; ++i) {
    const char* p = buf + aro + (MH * 2 + i) * 2048;
    aR[i][0] = *(const bf16x8*)(p + sk0);
    aR[i][1] = *(const bf16x8*)(p + sk1);
  }
}
template <int NF0, int NN>
static __device__ __forceinline__ void readBN(
    bf16x8 (&bb)[NN][2], const char* buf, int bro, int sk0, int sk1) {
#pragma unroll
  for (int j = 0; j < NN; ++j) {
    const char* p = buf + bro + (NF0 + j) * 2048;
    bb[j][0] = *(const bf16x8*)(p + sk0);
    bb[j][1] = *(const bf16x8*)(p + sk1);
  }
}
template <int MH, int NF0, int NN>
static __device__ __forceinline__ void quadN(
    f32x4 (&acc)[4][9], const bf16x8 (&aR)[2][2], const bf16x8 (&bb)[NN][2]) {
  __builtin_amdgcn_s_setprio(1);
#pragma unroll
  for (int i = 0; i < 2; ++i)
#pragma unroll
    for (int j = 0; j < NN; ++j)
#pragma unroll
      for (int ks = 0; ks < 2; ++ks)
        acc[MH * 2 + i][NF0 + j] = __builtin_amdgcn_mfma_f32_16x16x32_bf16(
            aR[i][ks], bb[j][ks], acc[MH * 2 + i][NF0 + j], 0, 0, 0);
  __builtin_amdgcn_s_setprio(0);
}

__global__ __launch_bounds__(512, 2) void gemm1_8ph(
    const __bf16* __restrict__ A, const __bf16* __restrict__ Bw,
    __bf16* __restrict__ C, int M, int N, int K) {
  __shared__ __align__(16) char lds[139264];
  char* const A0 = lds;                 // 32KB
  char* const A1 = lds + 32768;         // 32KB
  char* const B0 = lds + 65536;         // 36KB
  char* const B1 = lds + 102400;        // 36KB

  const int tid = threadIdx.x;
  const int l   = tid & 63;
  const int w   = tid >> 6;        // 0..7
  const int wm  = w >> 1;          // 0..3 (M quarter, 64 rows)
  const int wn  = w & 1;           // 0..1 (N half, 144 cols)
  const int lm  = l & 15;
  const int lq  = l >> 4;

  // XCD-aware bijective tile swizzle (grid 16x16 = 256, %8==0)
  const int nnt = 16;
  const int nwg = gridDim.x * gridDim.y;        // 256
  const int lid = blockIdx.y * gridDim.x + blockIdx.x;
  const int swz = (lid & 7) * (nwg >> 3) + (lid >> 3);
  const int m0  = (swz / nnt) * 256;
  const int n0  = (swz % nnt) * 288;

  const int aro = (wm * 64 + lm) * 128;
  const int bro = (wn * 144 + lm) * 128;
  const int sk0 = ((lq) ^ (lm & 7)) * 16;
  const int sk1 = ((4 + lq) ^ (lm & 7)) * 16;

  const int ssl = ((l & 7) ^ ((l >> 3) & 7)) * 8;
  auto stageA = [&](int grow0, int k0, char* dst) {
#pragma unroll
    for (int q2 = 0; q2 < 2; ++q2) {
      const int c   = w * 2 + q2;
      const int row = c * 8 + (l >> 3);
      g2lds16(A + (size_t)(grow0 + row) * K + k0 + ssl, dst + c * 1024);
    }
  };
  auto stageB = [&](int grow0, int k0, char* dst) {
#pragma unroll
    for (int q2 = 0; q2 < 2; ++q2) {
      const int c   = w * 2 + q2;
      const int row = c * 8 + (l >> 3);
      g2lds16(Bw + (size_t)(grow0 + row) * K + k0 + ssl, dst + c * 1024);
    }
    if (w < 2) {
      const int c   = 16 + w;
      const int row = c * 8 + (l >> 3);
      g2lds16(Bw + (size_t)(grow0 + row) * K + k0 + ssl, dst + c * 1024);
    }
  };

  f32x4 acc[4][9] = {};
  bf16x8 aL[2][2], aH[2][2], b5[5][2], b4[4][2];

  // prologue: tile0 A0/B0 + hi-tile A1 (B1 staged in ph0-1 of iter 0)
  stageA(m0,       0,  A0);
  stageA(m0 + 128, 0,  A0 + 16384);
  stageB(n0,       0,  B0);
  stageB(n0 + 144, 0,  B0 + 18432);
  stageA(m0,       64, A1);
  stageA(m0 + 128, 64, A1 + 16384);

  const int NIT = K >> 7;   // 12 iterations x 2 K-tiles
  for (int it = 0; it < NIT; ++it) {
    const int kh  = it * 128 + 64;
    const int knl = it * 128 + 128;  // last iter: benign OOB-read into
    const int knh = it * 128 + 192;  //  adjacent workspace, never consumed
    // ph0: stage B1lo(kh); wait tile0 (A0+B0) landed; Q(Mlo,Nlo)
    stageB(n0, kh, B1);
    WAITVM6();
    BAR1();
    readA2<0>(aL, A0, aro, sk0, sk1);
    readBN<0, 5>(b5, B0, bro, sk0, sk1);
    WAITLGKM();
    quadN<0, 0, 5>(acc, aL, b5);
    BAR2();
    // ph1: Q(Mhi,Nlo)  (aL held for ph3)
    stageB(n0 + 144, kh, B1 + 18432);
    BAR1();
    readA2<1>(aH, A0, aro, sk0, sk1);
    WAITLGKM();
    quadN<1, 0, 5>(acc, aH, b5);
    BAR2();
    // ph2: stage A0'<-knl (A0 reads done ph1); Q(Mhi,Nhi)
    stageA(m0, knl, A0);
    BAR1();
    readBN<5, 4>(b4, B0, bro, sk0, sk1);
    WAITLGKM();
    quadN<1, 5, 4>(acc, aH, b4);
    BAR2();
    // ph3: Q(Mlo,Nhi)  (regs only)
    stageA(m0 + 128, knl, A0 + 16384);
    BAR1();
    quadN<0, 5, 4>(acc, aL, b4);
    BAR2();
    // ph4: hi K-tile (A1/B1); stage B0'<-knl (B0 reads done ph2)
    stageB(n0, knl, B0);
    WAITVM6();
    BAR1();
    readA2<0>(aL, A1, aro, sk0, sk1);
    readBN<0, 5>(b5, B1, bro, sk0, sk1);
    WAITLGKM();
    quadN<0, 0, 5>(acc, aL, b5);
    BAR2();
    // ph5
    stageB(n0 + 144, knl, B0 + 18432);
    BAR1();
    readA2<1>(aH, A1, aro, sk0, sk1);
    WAITLGKM();
    quadN<1, 0, 5>(acc, aH, b5);
    BAR2();
    // ph6: stage A1'<-knh (A1 reads done ph5)
    stageA(m0, knh, A1);
    BAR1();
    readBN<5, 4>(b4, B1, bro, sk0, sk1);
    WAITLGKM();
    quadN<1, 5, 4>(acc, aH, b4);
    BAR2();
    // ph7
    stageA(m0 + 128, knh, A1 + 16384);
    BAR1();
    quadN<0, 5, 4>(acc, aL, b4);
    BAR2();
  }

  // epilogue: C/D layout col=lane&15, row=(lane>>4)*4+r (m89/m91 verified)
  const int r0 = lq * 4;
#pragma unroll
  for (int mf = 0; mf < 4; ++mf)
#pragma unroll
    for (int nf = 0; nf < 9; ++nf)
#pragma unroll
      for (int r = 0; r < 4; ++r) {
        const size_t row = (size_t)(m0 + wm * 64 + mf * 16 + r0 + r);
        const size_t col = (size_t)(n0 + wn * 144 + nf * 16 + lm);
        C[row * N + col] = (__bf16)acc[mf][nf][r];
      }
}

// ---------------------------------------------------------------------------
// GEMM2: 128x96 tile, BK=64, 8-phase (R8 schedule), fp32 out, 4 waves.
// Grid 16x32 = 512 blocks = exactly 2 blocks/CU (LDS 56KB) -> independent
// barriers decouple stalls (m97/m114 co-residency mechanism).
// Per-wave 64x48 = 4x3 frags (same as old gemm2 -> read/quad code reused).
// Staging: A = 16 granules (4/wave), B = 12 granules (3/wave), uniform.
// FIFO: prologue A0(4)+B0(3)+A1(4)=11; ph0 +B1(3)=14 -> vmcnt(7) keeps
// exactly A1+B1; ph4 symmetric. Anti-deps identical to verified R8.
// ---------------------------------------------------------------------------
template <int MH, int NF0, int NN>
static __device__ __forceinline__ void g2quad(
    f32x4 (&acc)[4][3], const bf16x8 (&aR)[2][2], const bf16x8 (&bb)[NN][2]) {
  __builtin_amdgcn_s_setprio(1);
#pragma unroll
  for (int i = 0; i < 2; ++i)
#pragma unroll
    for (int j = 0; j < NN; ++j)
#pragma unroll
      for (int ks = 0; ks < 2; ++ks)
        acc[MH * 2 + i][NF0 + j] = __builtin_amdgcn_mfma_f32_16x16x32_bf16(
            aR[i][ks], bb[j][ks], acc[MH * 2 + i][NF0 + j], 0, 0, 0);
  __builtin_amdgcn_s_setprio(0);
}

__global__ __launch_bounds__(256, 2) void gemm2_8ph(
    const __bf16* __restrict__ A, const __bf16* __restrict__ Bw,
    float* __restrict__ C, int M, int N, int K) {
  __shared__ __align__(16) char lds[57344];
  char* const A0 = lds;                 // 16KB (128r x 64c)
  char* const A1 = lds + 16384;         // 16KB
  char* const B0 = lds + 32768;         // 12KB (96r x 64c)
  char* const B1 = lds + 45056;         // 12KB

  const int tid = threadIdx.x;
  const int l   = tid & 63;
  const int w   = tid >> 6;        // 0..3
  const int wm  = w >> 1;          // 0..1 (M half, 64 rows)
  const int wn  = w & 1;           // 0..1 (N half, 48 cols)
  const int lm  = l & 15;
  const int lq  = l >> 4;

  // XCD-aware bijective swizzle (grid 16x32 = 512, %8==0)
  const int nwg = gridDim.x * gridDim.y;        // 512
  const int lid = blockIdx.y * gridDim.x + blockIdx.x;
  const int swz = (lid & 7) * (nwg >> 3) + (lid >> 3);
  const int m0  = (swz / 16) * 128;
  const int n0  = (swz % 16) * 96;

  const int aro = (wm * 64 + lm) * 128;
  const int bro = (wn * 48 + lm) * 128;
  const int sk0 = ((lq) ^ (lm & 7)) * 16;
  const int sk1 = ((4 + lq) ^ (lm & 7)) * 16;

  const int ssl = ((l & 7) ^ ((l >> 3) & 7)) * 8;
  auto stageA = [&](int k0, char* dst) {          // 16 granules, 4/wave
#pragma unroll
    for (int q2 = 0; q2 < 4; ++q2) {
      const int c   = w * 4 + q2;
      const int row = c * 8 + (l >> 3);
      g2lds16(A + (size_t)(m0 + row) * K + k0 + ssl, dst + c * 1024);
    }
  };
  auto stageB = [&](int k0, char* dst) {          // 12 granules, 3/wave
#pragma unroll
    for (int q2 = 0; q2 < 3; ++q2) {
      const int c   = w * 3 + q2;
      const int row = c * 8 + (l >> 3);
      g2lds16(Bw + (size_t)(n0 + row) * K + k0 + ssl, dst + c * 1024);
    }
  };

  f32x4 acc[4][3] = {};
  bf16x8 aL[2][2], aH[2][2], bL[2][2], bH[1][2];

  // prologue: A0/B0 (tile lo) + A1 (tile hi); B1 staged in ph0 of iter 0.
  stageA(0,  A0);
  stageB(0,  B0);
  stageA(64, A1);                       // 11 outstanding/wave

  const int NIT = K >> 7;   // 12 iterations x 2 K-tiles
  for (int it = 0; it < NIT; ++it) {
    const int kh  = it * 128 + 64;
    const int knl = it * 128 + 128;  // last iter: benign OOB-read
    const int knh = it * 128 + 192;
    // ph0: stage B1<-kh; wait lo tile (A0+B0); Q(Mlo,Nlo01)
    stageB(kh, B1);
    WAITVM7();
    BAR1();
    readA2<0>(aL, A0, aro, sk0, sk1);
    readBN<0, 2>(bL, B0, bro, sk0, sk1);
    WAITLGKM();
    g2quad<0, 0, 2>(acc, aL, bL);
    BAR2();
    // ph1: Q(Mhi,Nlo01)
    BAR1();
    readA2<1>(aH, A0, aro, sk0, sk1);
    WAITLGKM();
    g2quad<1, 0, 2>(acc, aH, bL);
    BAR2();
    // ph2: stage A0<-knl (A0 reads done ph1); Q(Mhi,Nhi2)
    stageA(knl, A0);
    BAR1();
    readBN<2, 1>(bH, B0, bro, sk0, sk1);
    WAITLGKM();
    g2quad<1, 2, 1>(acc, aH, bH);
    BAR2();
    // ph3: Q(Mlo,Nhi2) (regs only)
    BAR1();
    g2quad<0, 2, 1>(acc, aL, bH);
    BAR2();
    // ph4: hi K-tile; stage B0<-knl (B0 reads done ph2); wait A1+B1
    stageB(knl, B0);
    WAITVM7();
    BAR1();
    readA2<0>(aL, A1, aro, sk0, sk1);
    readBN<0, 2>(bL, B1, bro, sk0, sk1);
    WAITLGKM();
    g2quad<0, 0, 2>(acc, aL, bL);
    BAR2();
    // ph5
    BAR1();
    readA2<1>(aH, A1, aro, sk0, sk1);
    WAITLGKM();
    g2quad<1, 0, 2>(acc, aH, bL);
    BAR2();
    // ph6: stage A1<-knh (A1 reads done ph5)
    stageA(knh, A1);
    BAR1();
    readBN<2, 1>(bH, B1, bro, sk0, sk1);
    WAITLGKM();
    g2quad<1, 2, 1>(acc, aH, bH);
    BAR2();
    // ph7
    BAR1();
    g2quad<0, 2, 1>(acc, aL, bH);
    BAR2();
  }

  // epilogue: fp32 stores; tile col span 96*4B = 3 whole 128B lines.
  const int r0 = lq * 4;
#pragma unroll
  for (int mf = 0; mf < 4; ++mf)
#pragma unroll
    for (int nf = 0; nf < 3; ++nf)
#pragma unroll
      for (int r = 0; r < 4; ++r) {
        const size_t row = (size_t)(m0 + wm * 64 + mf * 16 + r0 + r);
        const size_t col = (size_t)(n0 + wn * 48 + nf * 16 + lm);
        C[row * N + col] = acc[mf][nf][r];
      }
}

// ---------------------------------------------------------------------------
// Fused: qk RMS-norm + 3D RoPE (blocks 0..NR_BLOCKS-1) AND V transpose
// (blocks NR_BLOCKS..NR_BLOCKS+1023). (byte-identical to R13)
// ---------------------------------------------------------------------------
static __device__ __forceinline__ float rope_one(float v, float p, int d,
                                                 const float* c3) {
  const int a  = d >> 5;        // which of 3 coord axes (d3=32)
  const int j  = d & 31;
  const int jj = j & 15;        // half=16
  const float invf = fexp2((float)jj * -0.8304820237218406f);
  const float ang  = c3[a] * invf;
  float sn, cs;
  __sincosf(ang, &sn, &cs);
  return (j < 16) ? (v * cs - p * sn) : (v * cs + p * sn);
}

__global__ __launch_bounds__(256) void normrope_tv(
    const __bf16* __restrict__ qkv, const float* __restrict__ coords,
    const int* __restrict__ ttype, const float* __restrict__ qsc,
    const float* __restrict__ ksc, __bf16* __restrict__ qo,
    __bf16* __restrict__ ko, __bf16* __restrict__ vo) {
  __shared__ __align__(16) __bf16 tile[96][72];   // tv role only (13.8KB)
  if ((int)blockIdx.x < NR_BLOCKS) {
    // ---- normrope role ----
    const int l   = threadIdx.x & 63;
    const int w   = threadIdx.x >> 6;
    const int rid = blockIdx.x * 4 + w;       // (b*T+t)*H + h
    const int h   = rid & (NH - 1);
    const int bt  = rid >> 4;
    const int t   = bt & (NT - 1);
    const int b   = bt >> 11;                 // T = 2048
    const __bf16* base = qkv + (size_t)bt * NQKV + h * ND;
    const float*  c3   = coords + (size_t)bt * 3;
    const bool rope    = ttype[bt] > 0;
    const size_t bh    = (size_t)(b * NH + h);

    // ---- q ----
    {
      float x0 = (float)base[l];
      float x1 = (l < 32) ? (float)base[64 + l] : 0.f;
      float ss = x0 * x0 + x1 * x1;
#pragma unroll
      for (int off = 1; off < 64; off <<= 1) ss += __shfl_xor(ss, off, 64);
      const float rn = rsqrtf(ss * (1.f / 96.f) + 1e-6f);
      x0 *= rn * qsc[l];
      if (l < 32) x1 *= rn * qsc[64 + l];
      const float p0 = __shfl_xor(x0, 16, 64);
      const float p1 = __shfl_xor(x1, 16, 64);
      if (rope) {
        x0 = rope_one(x0, p0, l, c3);
        if (l < 32) x1 = rope_one(x1, p1, 64 + l, c3);
      }
      __bf16* dst = qo + (bh * NT + t) * ND;
      dst[l] = (__bf16)x0;
      if (l < 32) dst[64 + l] = (__bf16)x1;
    }
    // ---- k ----
    {
      float x0 = (float)base[NC + l];
      float x1 = (l < 32) ? (float)base[NC + 64 + l] : 0.f;
      float ss = x0 * x0 + x1 * x1;
#pragma unroll
      for (int off = 1; off < 64; off <<= 1) ss += __shfl_xor(ss, off, 64);
      const float rn = rsqrtf(ss * (1.f / 96.f) + 1e-6f);
      x0 *= rn * ksc[l];
      if (l < 32) x1 *= rn * ksc[64 + l];
      const float p0 = __shfl_xor(x0, 16, 64);
      const float p1 = __shfl_xor(x1, 16, 64);
      if (rope) {
        x0 = rope_one(x0, p0, l, c3);
        if (l < 32) x1 = rope_one(x1, p1, 64 + l, c3);
      }
      __bf16* dst = ko + (bh * NT + t) * ND;
      dst[l] = (__bf16)x0;
      if (l < 32) dst[64 + l] = (__bf16)x1;
    }
    return;
  }
  // ---- tv role: 64-token transpose tile ----
  const int bx2 = blockIdx.x - NR_BLOCKS;   // 0..1023
  const int bh  = bx2 >> 5;                 // 0..31
  const int t0  = (bx2 & 31) * 64;
  const int tid = threadIdx.x;
  const int tok = tid & 63;
  const int grp = tid >> 6;                 // 0..3
  const int b   = bh >> 4, h = bh & 15;
  const __bf16* src =
      qkv + ((size_t)(b * NT + t0 + tok)) * NQKV + 2 * NC + h * ND;
#pragma unroll
  for (int q2 = 0; q2 < 3; ++q2) {
    const int ch = grp * 3 + q2;            // 12 chunks of 8 d
    bf16x8 v = *(const bf16x8*)(src + ch * 8);
#pragma unroll
    for (int j = 0; j < 8; ++j) tile[ch * 8 + j][tok] = v[j];
  }
  __syncthreads();
#pragma unroll
  for (int k2 = 0; k2 < 3; ++k2) {
    const int c  = tid + k2 * 256;          // 0..767
    const int d  = c >> 3;                  // 0..95
    const int tc = c & 7;                   // 0..7
    bf16x8 v = *(const bf16x8*)(&tile[d][tc * 8]);
    *(bf16x8*)(vo + ((size_t)bh * ND + d) * NT + t0 + tc * 8) = v;
  }
}

// ---------------------------------------------------------------------------
// Flash attention, KVBLK=64, fixed-max softmax, LDS-staged K/V (dbuf),
// XCD-L2 block remap, mirrored q-pairs. (byte-identical to R13)
// ---------------------------------------------------------------------------
static __device__ __forceinline__ void attn_tile64(
    const bf16x8 (&aq)[3], const bf16x8 (&bk)[4][3], int q0r, int n0,
    int lm, int lq, f32x4& lsum, __bf16* pbase /* [2][16][40] */) {
  f32x4 s[4];
#pragma unroll
  for (int nt = 0; nt < 4; ++nt) {
    f32x4 a = {};
#pragma unroll
    for (int c = 0; c < 3; ++c)
      a = __builtin_amdgcn_mfma_f32_16x16x32_bf16(aq[c], bk[nt][c], a, 0, 0, 0);
    s[nt] = a;
  }
  if (n0 + 63 > q0r) {   // diagonal-straddling tile(s): causal mask
#pragma unroll
    for (int nt = 0; nt < 4; ++nt)
#pragma unroll
      for (int r = 0; r < 4; ++r)
        if (n0 + nt * 16 + lm > q0r + lq * 4 + r) s[nt][r] = -1e30f;
  }
  const float cl = 0.10206207261596575f * 1.4426950408889634f;
#pragma unroll
  for (int nt = 0; nt < 4; ++nt)
#pragma unroll
    for (int r = 0; r < 4; ++r)
      s[nt][r] = fexp2((s[nt][r] - 96.0f) * cl);
#pragma unroll
  for (int r = 0; r < 4; ++r)
    lsum[r] += (s[0][r] + s[1][r]) + (s[2][r] + s[3][r]);
#pragma unroll
  for (int nt = 0; nt < 4; ++nt)
#pragma unroll
    for (int r = 0; r < 4; ++r)
      pbase[(nt >> 1) * 640 + (lq * 4 + r) * 40 + (nt & 1) * 16 + lm] =
          (__bf16)s[nt][r];
}

__global__ __launch_bounds__(512) void attn_fwd2(
    const __bf16* __restrict__ q, const __bf16* __restrict__ k,
    const __bf16* __restrict__ vt, __bf16* __restrict__ out) {
  __shared__ __align__(16) char KV[2][24576];        // [buf][K 12KB | V 12KB]
  __shared__ __align__(16) __bf16 plds[8][2][2][16][40];
  const int tid = threadIdx.x;
  const int l   = tid & 63;
  const int w   = tid >> 6;          // 0..7

  // XCD-L2 remap (bijective): i = by*8+bx; xcd=i&7; slot=i>>3;
  // bh = xcd + 8*(slot&3) (4 bh per XCD); qp = slot>>2 (0..7).
  const int i_  = blockIdx.y * 8 + blockIdx.x;
  const int slot = i_ >> 3;
  const int bh  = (i_ & 7) + 8 * (slot & 3);
  const int qp  = slot >> 2;         // 0..7

  const int lm  = l & 15;
  const int lq  = l >> 4;
  const int q0L = qp * 128 + w * 16;
  const int q0H = (15 - qp) * 128 + w * 16;
  const int nktLw = qp * 2 + (w >> 2) + 1;          // causal 64-tiles, frag L
  const int nktHw = (15 - qp) * 2 + (w >> 2) + 1;   // causal 64-tiles, frag H
  const int nkt   = (15 - qp) * 2 + 2;              // block loop bound
  const __bf16* qh = q  + (size_t)bh * NT * ND;
  const __bf16* kh = k  + (size_t)bh * NT * ND;
  const __bf16* vh = vt + (size_t)bh * ND * NT;
  __bf16* pbL = &plds[w][0][0][0][0];
  __bf16* pbH = &plds[w][1][0][0][0];

  // stage one 64-key tile: 24 granules of 1KB, 3 per wave (wave-uniform).
  auto stage = [&](int n0, char* buf) {
#pragma unroll
    for (int q2 = 0; q2 < 3; ++q2) {
      const int g = w * 3 + q2;
      if (g < 12) {                  // K granules (wave-uniform branch)
        const int nt = g / 3, c = g - nt * 3;
        g2lds16(kh + (size_t)(n0 + nt * 16 + (l >> 2)) * ND + c * 32 + (l & 3) * 8,
                buf + g * 1024);
      } else {                       // V granules
        const int gv = g - 12;
        const int dt = gv >> 1, hf = gv & 1;
        g2lds16(vh + (size_t)(dt * 16 + (l >> 2)) * NT + n0 + hf * 32 + (l & 3) * 8,
                buf + 12288 + gv * 1024);
      }
    }
  };

  bf16x8 aqL[3], aqH[3];
#pragma unroll
  for (int c = 0; c < 3; ++c) {
    aqL[c] = *(const bf16x8*)(qh + (size_t)(q0L + lm) * ND + c * 32 + lq * 8);
    aqH[c] = *(const bf16x8*)(qh + (size_t)(q0H + lm) * ND + c * 32 + lq * 8);
  }

  f32x4 oL[6] = {}, oH[6] = {};
  f32x4 lsL = {}, lsH = {};
  const int ji = (lm * 4 + lq) * 16;   // this lane's granule byte offset

  stage(0, KV[0]);
  for (int kt = 0; kt < nkt; ++kt) {
    __syncthreads();                   // drains stage(kt); all waves done kt-1
    if (kt + 1 < nkt) stage((kt + 1) * 64, KV[(kt + 1) & 1]);
    const char* Kc = KV[kt & 1];
    const char* Vc = KV[kt & 1] + 12288;
    const int n0 = kt * 64;
    bf16x8 bk[4][3];
#pragma unroll
    for (int nt = 0; nt < 4; ++nt)
#pragma unroll
      for (int c = 0; c < 3; ++c)
        bk[nt][c] = *(const bf16x8*)(Kc + (nt * 3 + c) * 1024 + ji);
    const bool doL = kt < nktLw;       // wave-uniform
    const bool doH = kt < nktHw;
    if (doL) attn_tile64(aqL, bk, q0L, n0, lm, lq, lsL, pbL);
    if (doH) attn_tile64(aqH, bk, q0H, n0, lm, lq, lsH, pbH);
    bf16x8 apL0 = {}, apL1 = {}, apH0 = {}, apH1 = {};
    if (doL) {
      apL0 = *(const bf16x8*)(pbL + lm * 40 + lq * 8);
      apL1 = *(const bf16x8*)(pbL + 640 + lm * 40 + lq * 8);
    }
    if (doH) {
      apH0 = *(const bf16x8*)(pbH + lm * 40 + lq * 8);
      apH1 = *(const bf16x8*)(pbH + 640 + lm * 40 + lq * 8);
    }
#pragma unroll
    for (int dt = 0; dt < 6; ++dt) {
      bf16x8 bv0 = *(const bf16x8*)(Vc + (dt * 2 + 0) * 1024 + ji);
      bf16x8 bv1 = *(const bf16x8*)(Vc + (dt * 2 + 1) * 1024 + ji);
      if (doL) {
        oL[dt] = __builtin_amdgcn_mfma_f32_16x16x32_bf16(apL0, bv0, oL[dt], 0, 0, 0);
        oL[dt] = __builtin_amdgcn_mfma_f32_16x16x32_bf16(apL1, bv1, oL[dt], 0, 0, 0);
      }
      if (doH) {
        oH[dt] = __builtin_amdgcn_mfma_f32_16x16x32_bf16(apH0, bv0, oH[dt], 0, 0, 0);
        oH[dt] = __builtin_amdgcn_mfma_f32_16x16x32_bf16(apH1, bv1, oH[dt], 0, 0, 0);
      }
    }
  }

  // epilogue: out[(b*T+t), h*96+d] for both frags
  const int b = bh >> 4, h = bh & 15;
#pragma unroll
  for (int f = 0; f < 2; ++f) {
    const f32x4* o = f ? oH : oL;
    const f32x4& ls = f ? lsH : lsL;
    const int q0 = f ? q0H : q0L;
    float rl[4];
#pragma unroll
    for (int r = 0; r < 4; ++r) {
      float v = ls[r];
#pragma unroll
      for (int off = 1; off < 16; off <<= 1) v += __shfl_xor(v, off, 64);
      rl[r] = 1.f / v;
    }
#pragma unroll
    for (int dt = 0; dt < 6; ++dt)
#pragma unroll
      for (int r = 0; r < 4; ++r) {
        const int t = q0 + lq * 4 + r;
        out[((size_t)(b * NT + t)) * NC + h * ND + dt * 16 + lm] =
            (__bf16)(o[dt][r] * rl[r]);
      }
  }
}

// ---------------------------------------------------------------------------
// workspace layout (bytes); attn-out aliases xb (dead after GEMM1)
// ---------------------------------------------------------------------------
static constexpr size_t OFF_XB   = 0;          // 12,582,912  (also attn out)
static constexpr size_t OFF_WQKV = 12582912;   // 14,155,776
static constexpr size_t OFF_WOUT = 26738688;   //  4,718,592
static constexpr size_t OFF_QKV  = 31457280;   // 37,748,736
static constexpr size_t OFF_Q    = 69206016;   // 12,582,912
static constexpr size_t OFF_K    = 81788928;   // 12,582,912
static constexpr size_t OFF_VT   = 94371840;   // 12,582,912  -> end 106,954,752

extern "C" void kernel_launch(void* const* d_in, const int* in_sizes, int n_in,
                              void* d_out, int out_size, void* d_ws,
                              size_t ws_size, hipStream_t stream) {
  const float* x      = (const float*)d_in[0];
  const float* coords = (const float*)d_in[1];
  const int*   ttype  = (const int*)d_in[2];
  const float* wqkv   = (const float*)d_in[3];
  const float* wout   = (const float*)d_in[4];
  const float* qs     = (const float*)d_in[5];
  const float* ks     = (const float*)d_in[6];

  char* ws = (char*)d_ws;
  __bf16* xb    = (__bf16*)(ws + OFF_XB);
  __bf16* wqkvb = (__bf16*)(ws + OFF_WQKV);
  __bf16* woutb = (__bf16*)(ws + OFF_WOUT);
  __bf16* qkvb  = (__bf16*)(ws + OFF_QKV);
  __bf16* qb    = (__bf16*)(ws + OFF_Q);
  __bf16* kb    = (__bf16*)(ws + OFF_K);
  __bf16* vtb   = (__bf16*)(ws + OFF_VT);
  __bf16* attnb = (__bf16*)(ws + OFF_XB);   // alias

  // 1. fp32 -> bf16 conversions (single launch)
  {
    const int n4x = NM * NC / 4;            // 1,572,864
    const int n4w = NQKV * NC / 4;          // 1,769,472
    const int n4o = NC * NC / 4;            //   589,824
    const int nblk = (n4x + n4w + n4o) / 256;
    cvt3_f32_bf16<<<nblk, 256, 0, stream>>>(
        (const float4*)x, (bf16x4*)xb, n4x,
        (const float4*)wqkv, (bf16x4*)wqkvb, n4w,
        (const float4*)wout, (bf16x4*)woutb);
  }
  // 2. qkv = x @ W_qkv^T  (bf16 out, 256x288 8-phase, grid 16x16=256)
  gemm1_8ph<<<dim3(NQKV / 288, NM / 256), 512, 0, stream>>>(
      xb, wqkvb, qkvb, NM, NQKV, NC);
  // 3. fused qk-norm+rope AND v-transpose (one launch)
  normrope_tv<<<NR_BLOCKS + 1024, 256, 0, stream>>>(
      qkvb, coords, ttype, qs, ks, qb, kb, vtb);
  // 4. causal attention (KVBLK=64, XCD-L2 remap, mirrored q-pairs)
  attn_fwd2<<<dim3(8, NB * NH), 512, 0, stream>>>(qb, kb, vtb, attnb);
  // 5. out = attn @ W_out^T (fp32, 128x96 8-phase, grid 16x32=512, 2/CU)
  gemm2_8ph<<<dim3(NC / 96, NM / 128), 256, 0, stream>>>(
      attnb, woutb, (float*)d_out, NM, NC, NC);
}

// Round 13
// 263.797 us; speedup vs baseline: 1.0960x; 1.0817x over previous
//
#include <hip/hip_runtime.h>
#include <stdint.h>
#include <stddef.h>

// ---------------------------------------------------------------------------
// CausalSelfAttention forward, MI355X/gfx950.
// Pipeline: cvt3(fp32->bf16) -> GEMM1(qkv 256x288 8-phase, FUSED epilogue:
//           qk norm+rope + v-transpose) -> attn_fwd2(KVBLK=64, mirrored,
//           XCD-remap) -> GEMM2(out proj, fp32, 128x192 8-phase)
// R17: R16 failed correctness (absmax 4.35). Root cause: V-transpose dst
//      used token stride 4096 (=NM, wrong) instead of 2048 (=NT) and the
//      global M-row instead of t = row & 2047 (batch already in bh).
//      One-line fix; everything else byte-identical to R16. Full epilogue
//      re-audit found no other index errors (q/k dst, rope pairing, scale
//      indexing, LDS stage mapping all verified).
// ---------------------------------------------------------------------------

typedef __attribute__((ext_vector_type(8))) __bf16 bf16x8;
typedef __attribute__((ext_vector_type(4))) __bf16 bf16x4;
typedef __attribute__((ext_vector_type(4))) float  f32x4;

#define NB 2
#define NT 2048
#define NC 1536
#define NH 16
#define ND 96
#define NQKV 4608          // 3*NC
#define NM 4096            // NB*NT

static __device__ __forceinline__ float fexp2(float x) {
#if __has_builtin(__builtin_amdgcn_exp2f)
  return __builtin_amdgcn_exp2f(x);
#else
  return exp2f(x);
#endif
}

// async global->LDS, 16B per lane; LDS dest = wave-uniform base + lane*16
static __device__ __forceinline__ void g2lds16(const void* g, void* l) {
  __builtin_amdgcn_global_load_lds(
      (const __attribute__((address_space(1))) void*)g,
      (__attribute__((address_space(3))) void*)l, 16, 0, 0);
}

// ---------------------------------------------------------------------------
// fp32 -> bf16 conversion, all three tensors in one launch.
// ---------------------------------------------------------------------------
__global__ __launch_bounds__(256) void cvt3_f32_bf16(
    const float4* __restrict__ sx, bf16x4* __restrict__ dx, int n4x,
    const float4* __restrict__ sw, bf16x4* __restrict__ dw, int n4w,
    const float4* __restrict__ so, bf16x4* __restrict__ do_) {
  int i = blockIdx.x * 256 + threadIdx.x;
  const float4* s;
  bf16x4* d;
  if (i < n4x)            { s = sx + i;               d = dx + i; }
  else if (i < n4x + n4w) { s = sw + (i - n4x);       d = dw + (i - n4x); }
  else                    { s = so + (i - n4x - n4w); d = do_ + (i - n4x - n4w); }
  float4 v = *s;
  bf16x4 o;
  o[0] = (__bf16)v.x; o[1] = (__bf16)v.y;
  o[2] = (__bf16)v.z; o[3] = (__bf16)v.w;
  *d = o;
}

// ---------------------------------------------------------------------------
// shared 8-phase helpers
// ---------------------------------------------------------------------------
#define BAR1() do { __builtin_amdgcn_s_barrier(); \
                    asm volatile("" ::: "memory"); } while (0)
#define BAR2() do { asm volatile("" ::: "memory"); \
                    __builtin_amdgcn_s_barrier(); } while (0)
#define WAITLGKM() do { asm volatile("s_waitcnt lgkmcnt(0)" ::: "memory"); \
                        __builtin_amdgcn_sched_barrier(0); } while (0)
#define WAITVM6() asm volatile("s_waitcnt vmcnt(6)" ::: "memory")
#define WAITVM5() asm volatile("s_waitcnt vmcnt(5)" ::: "memory")

// ---------------------------------------------------------------------------
// GEMM1: 256x288 tile, BK=64, 8-phase schedule (R8 schedule, main loop
// byte-identical). R16/R17: fused epilogue (qk norm+rope, v transpose).
// ---------------------------------------------------------------------------
template <int MH>
static __device__ __forceinline__ void readA2(
    bf16x8 (&aR)[2][2], const char* buf, int aro, int sk0, int sk1) {
#pragma unroll
  for (int i = 0; i < 2; ++i) {
    const char* p = buf + aro + (MH * 2 + i) * 2048;
    aR[i][0] = *(const bf16x8*)(p + sk0);
    aR[i][1] = *(const bf16x8*)(p + sk1);
  }
}
template <int NF0, int NN>
static __device__ __forceinline__ void readBN(
    bf16x8 (&bb)[NN][2], const char* buf, int bro, int sk0, int sk1) {
#pragma unroll
  for (int j = 0; j < NN; ++j) {
    const char* p = buf + bro + (NF0 + j) * 2048;
    bb[j][0] = *(const bf16x8*)(p + sk0);
    bb[j][1] = *(const bf16x8*)(p + sk1);
  }
}
template <int MH, int NF0, int NN>
static __device__ __forceinline__ void quadN(
    f32x4 (&acc)[4][9], const bf16x8 (&aR)[2][2], const bf16x8 (&bb)[NN][2]) {
  __builtin_amdgcn_s_setprio(1);
#pragma unroll
  for (int i = 0; i < 2; ++i)
#pragma unroll
    for (int j = 0; j < NN; ++j)
#pragma unroll
      for (int ks = 0; ks < 2; ++ks)
        acc[MH * 2 + i][NF0 + j] = __builtin_amdgcn_mfma_f32_16x16x32_bf16(
            aR[i][ks], bb[j][ks], acc[MH * 2 + i][NF0 + j], 0, 0, 0);
  __builtin_amdgcn_s_setprio(0);
}

__global__ __launch_bounds__(512) void gemm1_8ph(
    const __bf16* __restrict__ A, const __bf16* __restrict__ Bw,
    const float* __restrict__ coords, const int* __restrict__ ttype,
    const float* __restrict__ qsc, const float* __restrict__ ksc,
    __bf16* __restrict__ qo, __bf16* __restrict__ ko,
    __bf16* __restrict__ vo, int M, int N, int K) {
  __shared__ __align__(16) char lds[139264];
  char* const A0 = lds;                 // 32KB
  char* const A1 = lds + 32768;         // 32KB
  char* const B0 = lds + 65536;         // 36KB
  char* const B1 = lds + 102400;        // 36KB

  const int tid = threadIdx.x;
  const int l   = tid & 63;
  const int w   = tid >> 6;        // 0..7
  const int wm  = w >> 1;          // 0..3 (M quarter, 64 rows)
  const int wn  = w & 1;           // 0..1 (N half, 144 cols)
  const int lm  = l & 15;
  const int lq  = l >> 4;

  // XCD-aware bijective tile swizzle (grid 16x16 = 256, %8==0)
  const int nnt = 16;
  const int nwg = gridDim.x * gridDim.y;        // 256
  const int lid = blockIdx.y * gridDim.x + blockIdx.x;
  const int swz = (lid & 7) * (nwg >> 3) + (lid >> 3);
  const int m0  = (swz / nnt) * 256;
  const int n0  = (swz % nnt) * 288;

  const int aro = (wm * 64 + lm) * 128;
  const int bro = (wn * 144 + lm) * 128;
  const int sk0 = ((lq) ^ (lm & 7)) * 16;
  const int sk1 = ((4 + lq) ^ (lm & 7)) * 16;

  const int ssl = ((l & 7) ^ ((l >> 3) & 7)) * 8;
  auto stageA = [&](int grow0, int k0, char* dst) {
#pragma unroll
    for (int q2 = 0; q2 < 2; ++q2) {
      const int c   = w * 2 + q2;
      const int row = c * 8 + (l >> 3);
      g2lds16(A + (size_t)(grow0 + row) * K + k0 + ssl, dst + c * 1024);
    }
  };
  auto stageB = [&](int grow0, int k0, char* dst) {
#pragma unroll
    for (int q2 = 0; q2 < 2; ++q2) {
      const int c   = w * 2 + q2;
      const int row = c * 8 + (l >> 3);
      g2lds16(Bw + (size_t)(grow0 + row) * K + k0 + ssl, dst + c * 1024);
    }
    if (w < 2) {
      const int c   = 16 + w;
      const int row = c * 8 + (l >> 3);
      g2lds16(Bw + (size_t)(grow0 + row) * K + k0 + ssl, dst + c * 1024);
    }
  };

  f32x4 acc[4][9] = {};
  bf16x8 aL[2][2], aH[2][2], b5[5][2], b4[4][2];

  // prologue: tile0 A0/B0 + hi-tile A1 (B1 staged in ph0-1 of iter 0)
  stageA(m0,       0,  A0);
  stageA(m0 + 128, 0,  A0 + 16384);
  stageB(n0,       0,  B0);
  stageB(n0 + 144, 0,  B0 + 18432);
  stageA(m0,       64, A1);
  stageA(m0 + 128, 64, A1 + 16384);

  const int NIT = K >> 7;   // 12 iterations x 2 K-tiles
  for (int it = 0; it < NIT; ++it) {
    const int kh  = it * 128 + 64;
    const int knl = it * 128 + 128;  // last iter: benign OOB-read into
    const int knh = it * 128 + 192;  //  adjacent workspace, never consumed
    // ph0: stage B1lo(kh); wait tile0 (A0+B0) landed; Q(Mlo,Nlo)
    stageB(n0, kh, B1);
    WAITVM6();
    BAR1();
    readA2<0>(aL, A0, aro, sk0, sk1);
    readBN<0, 5>(b5, B0, bro, sk0, sk1);
    WAITLGKM();
    quadN<0, 0, 5>(acc, aL, b5);
    BAR2();
    // ph1: Q(Mhi,Nlo)  (aL held for ph3)
    stageB(n0 + 144, kh, B1 + 18432);
    BAR1();
    readA2<1>(aH, A0, aro, sk0, sk1);
    WAITLGKM();
    quadN<1, 0, 5>(acc, aH, b5);
    BAR2();
    // ph2: stage A0'<-knl (A0 reads done ph1); Q(Mhi,Nhi)
    stageA(m0, knl, A0);
    BAR1();
    readBN<5, 4>(b4, B0, bro, sk0, sk1);
    WAITLGKM();
    quadN<1, 5, 4>(acc, aH, b4);
    BAR2();
    // ph3: Q(Mlo,Nhi)  (regs only)
    stageA(m0 + 128, knl, A0 + 16384);
    BAR1();
    quadN<0, 5, 4>(acc, aL, b4);
    BAR2();
    // ph4: hi K-tile (A1/B1); stage B0'<-knl (B0 reads done ph2)
    stageB(n0, knl, B0);
    WAITVM6();
    BAR1();
    readA2<0>(aL, A1, aro, sk0, sk1);
    readBN<0, 5>(b5, B1, bro, sk0, sk1);
    WAITLGKM();
    quadN<0, 0, 5>(acc, aL, b5);
    BAR2();
    // ph5
    stageB(n0 + 144, knl, B0 + 18432);
    BAR1();
    readA2<1>(aH, A1, aro, sk0, sk1);
    WAITLGKM();
    quadN<1, 0, 5>(acc, aH, b5);
    BAR2();
    // ph6: stage A1'<-knh (A1 reads done ph5)
    stageA(m0, knh, A1);
    BAR1();
    readBN<5, 4>(b4, B1, bro, sk0, sk1);
    WAITLGKM();
    quadN<1, 5, 4>(acc, aH, b4);
    BAR2();
    // ph7
    stageA(m0 + 128, knh, A1 + 16384);
    BAR1();
    quadN<0, 5, 4>(acc, aL, b4);
    BAR2();
  }

  // ================= fused epilogue (R17: V-dst index fixed) =============
  asm volatile("s_waitcnt vmcnt(0)" ::: "memory");
  __syncthreads();
  constexpr int S = 296;                 // LDS row stride elems (592B)
  __bf16* cl = (__bf16*)lds;             // [128][S] = 75.8KB
  const int bI = m0 >> 11;               // batch index (no tile straddles)
  const float IF[16] = {                 // 10000^(-jj/16) = 10^(-jj/4)
      1.0f, 0.5623413251903491f, 0.31622776601683794f, 0.17782794100389226f,
      0.1f, 0.05623413251903491f, 0.03162277660168379f,
      0.017782794100389229f, 0.01f, 0.005623413251903491f,
      0.0031622776601683794f, 0.0017782794100389228f, 0.001f,
      0.0005623413251903491f, 0.00031622776601683794f,
      0.00017782794100389227f};
  for (int half = 0; half < 2; ++half) {
    if ((wm >> 1) == half) {
#pragma unroll
      for (int mf = 0; mf < 4; ++mf)
#pragma unroll
        for (int nf = 0; nf < 9; ++nf)
#pragma unroll
          for (int r = 0; r < 4; ++r)
            cl[((wm & 1) * 64 + mf * 16 + lq * 4 + r) * S + wn * 144 +
               nf * 16 + lm] = (__bf16)acc[mf][nf][r];
    }
    __syncthreads();
    const int rbase = m0 + half * 128;
    const int tb    = rbase & 2047;      // token base within batch
    const int nact  = half ? 512 : 256;
    if (tid < nact) {
      // ---- q/k heads ----
      for (int tk = tid; tk < 384; tk += nact) {
        const int j    = tk >> 7;
        const int rowl = tk & 127;
        const int g    = n0 / 96 + j;     // global head 0..47
        const int ty   = g >> 4;          // 0 q, 1 k, 2 v
        if (ty < 2) {
          const int hh   = g & 15;
          const int rowg = rbase + rowl;  // = b*2048 + t
          const float* c3 = coords + (size_t)rowg * 3;
          const bool rp   = ttype[rowg] > 0;
          const float* sc = ty ? ksc : qsc;
          const __bf16* lr = cl + rowl * S + j * 96;
          float ss = 0.f;
#pragma unroll
          for (int c8 = 0; c8 < 12; ++c8) {
            bf16x8 v = *(const bf16x8*)(lr + c8 * 8);
#pragma unroll
            for (int e = 0; e < 8; ++e) {
              const float f = (float)v[e];
              ss += f * f;
            }
          }
          const float rn = rsqrtf(ss * (1.f / 96.f) + 1e-6f);
          __bf16* dst = (ty ? ko : qo) +
              ((size_t)((bI * 16 + hh) * 2048 + (rowg & 2047))) * 96;
#pragma unroll
          for (int a = 0; a < 3; ++a) {
            const float ca = c3[a];
            float xl[16], xh[16];
            bf16x8 v0 = *(const bf16x8*)(lr + a * 32);
            bf16x8 v1 = *(const bf16x8*)(lr + a * 32 + 8);
            bf16x8 v2 = *(const bf16x8*)(lr + a * 32 + 16);
            bf16x8 v3 = *(const bf16x8*)(lr + a * 32 + 24);
#pragma unroll
            for (int e = 0; e < 8; ++e) {
              xl[e]     = (float)v0[e] * rn * sc[a * 32 + e];
              xl[e + 8] = (float)v1[e] * rn * sc[a * 32 + 8 + e];
              xh[e]     = (float)v2[e] * rn * sc[a * 32 + 16 + e];
              xh[e + 8] = (float)v3[e] * rn * sc[a * 32 + 24 + e];
            }
            if (rp) {
#pragma unroll
              for (int e = 0; e < 16; ++e) {
                float sn, csn;
                __sincosf(ca * IF[e], &sn, &csn);
                const float lo = xl[e] * csn - xh[e] * sn;
                const float hi = xl[e] * sn + xh[e] * csn;
                xl[e] = lo;
                xh[e] = hi;
              }
            }
            bf16x8 o0, o1, o2, o3;
#pragma unroll
            for (int e = 0; e < 8; ++e) {
              o0[e] = (__bf16)xl[e];
              o1[e] = (__bf16)xl[e + 8];
              o2[e] = (__bf16)xh[e];
              o3[e] = (__bf16)xh[e + 8];
            }
            *(bf16x8*)(dst + a * 32)      = o0;
            *(bf16x8*)(dst + a * 32 + 8)  = o1;
            *(bf16x8*)(dst + a * 32 + 16) = o2;
            *(bf16x8*)(dst + a * 32 + 24) = o3;
          }
        }
      }
      // ---- v heads: LDS column transpose ----
#pragma unroll
      for (int j = 0; j < 3; ++j) {
        const int g = n0 / 96 + j;
        if (g >= 32) {
          const int hh = g & 15;
          for (int tk = tid; tk < 192; tk += nact) {
            const int d  = tk >> 1;
            const int sg = tk & 1;
            const __bf16* cp = cl + (sg * 64) * S + j * 96 + d;
            // R17 fix: vT token stride is NT=2048 and token = tb (+seg),
            // batch already folded into bh. (R16 had *4096 + rbase.)
            __bf16* vdst = vo +
                ((size_t)(bI * 16 + hh) * 96 + d) * 2048 + tb + sg * 64;
#pragma unroll
            for (int vv = 0; vv < 8; ++vv) {
              bf16x8 ov;
#pragma unroll
              for (int e = 0; e < 8; ++e) ov[e] = cp[(vv * 8 + e) * S];
              *(bf16x8*)(vdst + vv * 8) = ov;
            }
          }
        }
      }
    }
    __syncthreads();
  }
}

// ---------------------------------------------------------------------------
// GEMM2: 128x192 tile, BK=64, 8-phase (R8 schedule, R13 best), fp32 out.
// Grid 8x32 = 256 (zero tail). 8 waves = 2(M) x 4(N); per-wave 64x48.
// LDS 80KB. Uniform staging: A=2, B=3 loads/wave. vmcnt(5) at ph0/ph4.
// ---------------------------------------------------------------------------
template <int MH, int NF0, int NN>
static __device__ __forceinline__ void g2quad(
    f32x4 (&acc)[4][3], const bf16x8 (&aR)[2][2], const bf16x8 (&bb)[NN][2]) {
  __builtin_amdgcn_s_setprio(1);
#pragma unroll
  for (int i = 0; i < 2; ++i)
#pragma unroll
    for (int j = 0; j < NN; ++j)
#pragma unroll
      for (int ks = 0; ks < 2; ++ks)
        acc[MH * 2 + i][NF0 + j] = __builtin_amdgcn_mfma_f32_16x16x32_bf16(
            aR[i][ks], bb[j][ks], acc[MH * 2 + i][NF0 + j], 0, 0, 0);
  __builtin_amdgcn_s_setprio(0);
}

__global__ __launch_bounds__(512, 2) void gemm2_8ph(
    const __bf16* __restrict__ A, const __bf16* __restrict__ Bw,
    float* __restrict__ C, int M, int N, int K) {
  __shared__ __align__(16) char lds[81920];
  char* const A0 = lds;                 // 16KB
  char* const A1 = lds + 16384;         // 16KB
  char* const B0 = lds + 32768;         // 24KB
  char* const B1 = lds + 57344;         // 24KB

  const int tid = threadIdx.x;
  const int l   = tid & 63;
  const int w   = tid >> 6;        // 0..7
  const int wm  = w >> 2;          // 0..1 (M half)
  const int wn  = w & 3;           // 0..3 (N quarter)
  const int lm  = l & 15;
  const int lq  = l >> 4;

  const int nwg = gridDim.x * gridDim.y;        // 256
  const int lid = blockIdx.y * gridDim.x + blockIdx.x;
  const int swz = (lid & 7) * (nwg >> 3) + (lid >> 3);
  const int m0  = (swz / 8) * 128;
  const int n0  = (swz % 8) * 192;

  const int aro = (wm * 64 + lm) * 128;
  const int bro = (wn * 48 + lm) * 128;
  const int sk0 = ((lq) ^ (lm & 7)) * 16;
  const int sk1 = ((4 + lq) ^ (lm & 7)) * 16;

  const int ssl = ((l & 7) ^ ((l >> 3) & 7)) * 8;
  auto stageA = [&](int k0, char* dst) {          // 16 granules, 2/wave
#pragma unroll
    for (int q2 = 0; q2 < 2; ++q2) {
      const int c   = w * 2 + q2;
      const int row = c * 8 + (l >> 3);
      g2lds16(A + (size_t)(m0 + row) * K + k0 + ssl, dst + c * 1024);
    }
  };
  auto stageB = [&](int k0, char* dst) {          // 24 granules, 3/wave
#pragma unroll
    for (int q2 = 0; q2 < 3; ++q2) {
      const int c   = w * 3 + q2;
      const int row = c * 8 + (l >> 3);
      g2lds16(Bw + (size_t)(n0 + row) * K + k0 + ssl, dst + c * 1024);
    }
  };

  f32x4 acc[4][3] = {};
  bf16x8 aL[2][2], aH[2][2], bL[2][2], bH[1][2];

  // prologue: A0/B0 (tile lo) + A1 (tile hi); B1 staged in ph0 of iter 0.
  stageA(0,  A0);
  stageB(0,  B0);
  stageA(64, A1);                       // 7 outstanding/wave

  const int NIT = K >> 7;   // 12 iterations x 2 K-tiles
  for (int it = 0; it < NIT; ++it) {
    const int kh  = it * 128 + 64;
    const int knl = it * 128 + 128;  // last iter: benign OOB-read
    const int knh = it * 128 + 192;
    // ph0: stage B1<-kh; wait lo tile (A0+B0); Q(Mlo,Nlo01)
    stageB(kh, B1);
    WAITVM5();
    BAR1();
    readA2<0>(aL, A0, aro, sk0, sk1);
    readBN<0, 2>(bL, B0, bro, sk0, sk1);
    WAITLGKM();
    g2quad<0, 0, 2>(acc, aL, bL);
    BAR2();
    // ph1: Q(Mhi,Nlo01)
    BAR1();
    readA2<1>(aH, A0, aro, sk0, sk1);
    WAITLGKM();
    g2quad<1, 0, 2>(acc, aH, bL);
    BAR2();
    // ph2: stage A0<-knl (A0 reads done ph1); Q(Mhi,Nhi2)
    stageA(knl, A0);
    BAR1();
    readBN<2, 1>(bH, B0, bro, sk0, sk1);
    WAITLGKM();
    g2quad<1, 2, 1>(acc, aH, bH);
    BAR2();
    // ph3: Q(Mlo,Nhi2) (regs only)
    BAR1();
    g2quad<0, 2, 1>(acc, aL, bH);
    BAR2();
    // ph4: hi K-tile; stage B0<-knl (B0 reads done ph2); wait A1+B1
    stageB(knl, B0);
    WAITVM5();
    BAR1();
    readA2<0>(aL, A1, aro, sk0, sk1);
    readBN<0, 2>(bL, B1, bro, sk0, sk1);
    WAITLGKM();
    g2quad<0, 0, 2>(acc, aL, bL);
    BAR2();
    // ph5
    BAR1();
    readA2<1>(aH, A1, aro, sk0, sk1);
    WAITLGKM();
    g2quad<1, 0, 2>(acc, aH, bL);
    BAR2();
    // ph6: stage A1<-knh (A1 reads done ph5)
    stageA(knh, A1);
    BAR1();
    readBN<2, 1>(bH, B1, bro, sk0, sk1);
    WAITLGKM();
    g2quad<1, 2, 1>(acc, aH, bH);
    BAR2();
    // ph7
    BAR1();
    g2quad<0, 2, 1>(acc, aL, bH);
    BAR2();
  }

  // epilogue: fp32 stores; 192*4B tile pitch = whole 128B lines.
  const int r0 = lq * 4;
#pragma unroll
  for (int mf = 0; mf < 4; ++mf)
#pragma unroll
    for (int nf = 0; nf < 3; ++nf)
#pragma unroll
      for (int r = 0; r < 4; ++r) {
        const size_t row = (size_t)(m0 + wm * 64 + mf * 16 + r0 + r);
        const size_t col = (size_t)(n0 + wn * 48 + nf * 16 + lm);
        C[row * N + col] = acc[mf][nf][r];
      }
}

// ---------------------------------------------------------------------------
// Flash attention, KVBLK=64, fixed-max softmax, LDS-staged K/V (dbuf),
// XCD-L2 block remap, mirrored q-pairs. (byte-identical to R13)
// ---------------------------------------------------------------------------
static __device__ __forceinline__ void attn_tile64(
    const bf16x8 (&aq)[3], const bf16x8 (&bk)[4][3], int q0r, int n0,
    int lm, int lq, f32x4& lsum, __bf16* pbase /* [2][16][40] */) {
  f32x4 s[4];
#pragma unroll
  for (int nt = 0; nt < 4; ++nt) {
    f32x4 a = {};
#pragma unroll
    for (int c = 0; c < 3; ++c)
      a = __builtin_amdgcn_mfma_f32_16x16x32_bf16(aq[c], bk[nt][c], a, 0, 0, 0);
    s[nt] = a;
  }
  if (n0 + 63 > q0r) {   // diagonal-straddling tile(s): causal mask
#pragma unroll
    for (int nt = 0; nt < 4; ++nt)
#pragma unroll
      for (int r = 0; r < 4; ++r)
        if (n0 + nt * 16 + lm > q0r + lq * 4 + r) s[nt][r] = -1e30f;
  }
  const float cl = 0.10206207261596575f * 1.4426950408889634f;
#pragma unroll
  for (int nt = 0; nt < 4; ++nt)
#pragma unroll
    for (int r = 0; r < 4; ++r)
      s[nt][r] = fexp2((s[nt][r] - 96.0f) * cl);
#pragma unroll
  for (int r = 0; r < 4; ++r)
    lsum[r] += (s[0][r] + s[1][r]) + (s[2][r] + s[3][r]);
#pragma unroll
  for (int nt = 0; nt < 4; ++nt)
#pragma unroll
    for (int r = 0; r < 4; ++r)
      pbase[(nt >> 1) * 640 + (lq * 4 + r) * 40 + (nt & 1) * 16 + lm] =
          (__bf16)s[nt][r];
}

__global__ __launch_bounds__(512) void attn_fwd2(
    const __bf16* __restrict__ q, const __bf16* __restrict__ k,
    const __bf16* __restrict__ vt, __bf16* __restrict__ out) {
  __shared__ __align__(16) char KV[2][24576];        // [buf][K 12KB | V 12KB]
  __shared__ __align__(16) __bf16 plds[8][2][2][16][40];
  const int tid = threadIdx.x;
  const int l   = tid & 63;
  const int w   = tid >> 6;          // 0..7

  // XCD-L2 remap (bijective): i = by*8+bx; xcd=i&7; slot=i>>3;
  // bh = xcd + 8*(slot&3) (4 bh per XCD); qp = slot>>2 (0..7).
  const int i_  = blockIdx.y * 8 + blockIdx.x;
  const int slot = i_ >> 3;
  const int bh  = (i_ & 7) + 8 * (slot & 3);
  const int qp  = slot >> 2;         // 0..7

  const int lm  = l & 15;
  const int lq  = l >> 4;
  const int q0L = qp * 128 + w * 16;
  const int q0H = (15 - qp) * 128 + w * 16;
  const int nktLw = qp * 2 + (w >> 2) + 1;          // causal 64-tiles, frag L
  const int nktHw = (15 - qp) * 2 + (w >> 2) + 1;   // causal 64-tiles, frag H
  const int nkt   = (15 - qp) * 2 + 2;              // block loop bound
  const __bf16* qh = q  + (size_t)bh * NT * ND;
  const __bf16* kh = k  + (size_t)bh * NT * ND;
  const __bf16* vh = vt + (size_t)bh * ND * NT;
  __bf16* pbL = &plds[w][0][0][0][0];
  __bf16* pbH = &plds[w][1][0][0][0];

  // stage one 64-key tile: 24 granules of 1KB, 3 per wave (wave-uniform).
  auto stage = [&](int n0, char* buf) {
#pragma unroll
    for (int q2 = 0; q2 < 3; ++q2) {
      const int g = w * 3 + q2;
      if (g < 12) {                  // K granules (wave-uniform branch)
        const int nt = g / 3, c = g - nt * 3;
        g2lds16(kh + (size_t)(n0 + nt * 16 + (l >> 2)) * ND + c * 32 + (l & 3) * 8,
                buf + g * 1024);
      } else {                       // V granules
        const int gv = g - 12;
        const int dt = gv >> 1, hf = gv & 1;
        g2lds16(vh + (size_t)(dt * 16 + (l >> 2)) * NT + n0 + hf * 32 + (l & 3) * 8,
                buf + 12288 + gv * 1024);
      }
    }
  };

  bf16x8 aqL[3], aqH[3];
#pragma unroll
  for (int c = 0; c < 3; ++c) {
    aqL[c] = *(const bf16x8*)(qh + (size_t)(q0L + lm) * ND + c * 32 + lq * 8);
    aqH[c] = *(const bf16x8*)(qh + (size_t)(q0H + lm) * ND + c * 32 + lq * 8);
  }

  f32x4 oL[6] = {}, oH[6] = {};
  f32x4 lsL = {}, lsH = {};
  const int ji = (lm * 4 + lq) * 16;   // this lane's granule byte offset

  stage(0, KV[0]);
  for (int kt = 0; kt < nkt; ++kt) {
    __syncthreads();                   // drains stage(kt); all waves done kt-1
    if (kt + 1 < nkt) stage((kt + 1) * 64, KV[(kt + 1) & 1]);
    const char* Kc = KV[kt & 1];
    const char* Vc = KV[kt & 1] + 12288;
    const int n0 = kt * 64;
    bf16x8 bk[4][3];
#pragma unroll
    for (int nt = 0; nt < 4; ++nt)
#pragma unroll
      for (int c = 0; c < 3; ++c)
        bk[nt][c] = *(const bf16x8*)(Kc + (nt * 3 + c) * 1024 + ji);
    const bool doL = kt < nktLw;       // wave-uniform
    const bool doH = kt < nktHw;
    if (doL) attn_tile64(aqL, bk, q0L, n0, lm, lq, lsL, pbL);
    if (doH) attn_tile64(aqH, bk, q0H, n0, lm, lq, lsH, pbH);
    bf16x8 apL0 = {}, apL1 = {}, apH0 = {}, apH1 = {};
    if (doL) {
      apL0 = *(const bf16x8*)(pbL + lm * 40 + lq * 8);
      apL1 = *(const bf16x8*)(pbL + 640 + lm * 40 + lq * 8);
    }
    if (doH) {
      apH0 = *(const bf16x8*)(pbH + lm * 40 + lq * 8);
      apH1 = *(const bf16x8*)(pbH + 640 + lm * 40 + lq * 8);
    }
#pragma unroll
    for (int dt = 0; dt < 6; ++dt) {
      bf16x8 bv0 = *(const bf16x8*)(Vc + (dt * 2 + 0) * 1024 + ji);
      bf16x8 bv1 = *(const bf16x8*)(Vc + (dt * 2 + 1) * 1024 + ji);
      if (doL) {
        oL[dt] = __builtin_amdgcn_mfma_f32_16x16x32_bf16(apL0, bv0, oL[dt], 0, 0, 0);
        oL[dt] = __builtin_amdgcn_mfma_f32_16x16x32_bf16(apL1, bv1, oL[dt], 0, 0, 0);
      }
      if (doH) {
        oH[dt] = __builtin_amdgcn_mfma_f32_16x16x32_bf16(apH0, bv0, oH[dt], 0, 0, 0);
        oH[dt] = __builtin_amdgcn_mfma_f32_16x16x32_bf16(apH1, bv1, oH[dt], 0, 0, 0);
      }
    }
  }

  // epilogue: out[(b*T+t), h*96+d] for both frags
  const int b = bh >> 4, h = bh & 15;
#pragma unroll
  for (int f = 0; f < 2; ++f) {
    const f32x4* o = f ? oH : oL;
    const f32x4& ls = f ? lsH : lsL;
    const int q0 = f ? q0H : q0L;
    float rl[4];
#pragma unroll
    for (int r = 0; r < 4; ++r) {
      float v = ls[r];
#pragma unroll
      for (int off = 1; off < 16; off <<= 1) v += __shfl_xor(v, off, 64);
      rl[r] = 1.f / v;
    }
#pragma unroll
    for (int dt = 0; dt < 6; ++dt)
#pragma unroll
      for (int r = 0; r < 4; ++r) {
        const int t = q0 + lq * 4 + r;
        out[((size_t)(b * NT + t)) * NC + h * ND + dt * 16 + lm] =
            (__bf16)(o[dt][r] * rl[r]);
      }
  }
}

// ---------------------------------------------------------------------------
// workspace layout (bytes); attn-out aliases xb (dead after GEMM1)
// ---------------------------------------------------------------------------
static constexpr size_t OFF_XB   = 0;          // 12,582,912  (also attn out)
static constexpr size_t OFF_WQKV = 12582912;   // 14,155,776
static constexpr size_t OFF_WOUT = 26738688;   //  4,718,592
static constexpr size_t OFF_QKV  = 31457280;   // 37,748,736 (unused now)
static constexpr size_t OFF_Q    = 69206016;   // 12,582,912
static constexpr size_t OFF_K    = 81788928;   // 12,582,912
static constexpr size_t OFF_VT   = 94371840;   // 12,582,912  -> end 106,954,752

extern "C" void kernel_launch(void* const* d_in, const int* in_sizes, int n_in,
                              void* d_out, int out_size, void* d_ws,
                              size_t ws_size, hipStream_t stream) {
  const float* x      = (const float*)d_in[0];
  const float* coords = (const float*)d_in[1];
  const int*   ttype  = (const int*)d_in[2];
  const float* wqkv   = (const float*)d_in[3];
  const float* wout   = (const float*)d_in[4];
  const float* qs     = (const float*)d_in[5];
  const float* ks     = (const float*)d_in[6];

  char* ws = (char*)d_ws;
  __bf16* xb    = (__bf16*)(ws + OFF_XB);
  __bf16* wqkvb = (__bf16*)(ws + OFF_WQKV);
  __bf16* woutb = (__bf16*)(ws + OFF_WOUT);
  __bf16* qb    = (__bf16*)(ws + OFF_Q);
  __bf16* kb    = (__bf16*)(ws + OFF_K);
  __bf16* vtb   = (__bf16*)(ws + OFF_VT);
  __bf16* attnb = (__bf16*)(ws + OFF_XB);   // alias

  // 1. fp32 -> bf16 conversions (single launch)
  {
    const int n4x = NM * NC / 4;            // 1,572,864
    const int n4w = NQKV * NC / 4;          // 1,769,472
    const int n4o = NC * NC / 4;            //   589,824
    const int nblk = (n4x + n4w + n4o) / 256;
    cvt3_f32_bf16<<<nblk, 256, 0, stream>>>(
        (const float4*)x, (bf16x4*)xb, n4x,
        (const float4*)wqkv, (bf16x4*)wqkvb, n4w,
        (const float4*)wout, (bf16x4*)woutb);
  }
  // 2. qkv = x @ W_qkv^T with FUSED qk norm+rope and v-transpose epilogue
  gemm1_8ph<<<dim3(NQKV / 288, NM / 256), 512, 0, stream>>>(
      xb, wqkvb, coords, ttype, qs, ks, qb, kb, vtb, NM, NQKV, NC);
  // 3. causal attention (KVBLK=64, XCD-L2 remap, mirrored q-pairs)
  attn_fwd2<<<dim3(8, NB * NH), 512, 0, stream>>>(qb, kb, vtb, attnb);
  // 4. out = attn @ W_out^T (fp32 out, 128x192 8-phase, grid 8x32=256)
  gemm2_8ph<<<dim3(NC / 192, NM / 128), 512, 0, stream>>>(
      attnb, woutb, (float*)d_out, NM, NC, NC);
}